// Round 2
// baseline (497.396 us; speedup 1.0000x reference)
//
#include <hip/hip_runtime.h>
#include <math.h>

// Problem constants
#define NTOK 4096
#define PCH  128
#define ICH  256
#define OCH  128
#define NB   2
#define SCALEF 0.08838834764831845f   // 1/sqrt(128)
#define SCALE2 0.12751743f            // SCALEF * log2(e)

typedef __bf16 bf16_t;
typedef __attribute__((ext_vector_type(8))) __bf16 bf16x8;
typedef __attribute__((ext_vector_type(4))) __bf16 bf16x4;
typedef __attribute__((ext_vector_type(4))) float floatx4;

#define LDK 136   // padded row length (bf16) for k=128 tiles

// ---------------------------------------------------------------------------
// K0: merged pack — y<2: pf -> pfC + pfT;  y>=2: img -> imgT (token-major)
// ---------------------------------------------------------------------------
__global__ __launch_bounds__(256) void pack_all(const float* __restrict__ pf,
                                                const float* __restrict__ img,
                                                bf16_t* __restrict__ pfC,
                                                bf16_t* __restrict__ pfT,
                                                bf16_t* __restrict__ imgT)
{
    __shared__ float Ls[64][65];
    const int t = threadIdx.x;
    const int n0 = blockIdx.x * 64, b = blockIdx.z;
    const bool ispf = blockIdx.y < 2;
    const int d0 = ispf ? blockIdx.y * 64 : (blockIdx.y - 2) * 64;
    const float* src = (ispf ? pf + ((size_t)(b * PCH + d0)) * NTOK
                             : img + ((size_t)(b * ICH + d0)) * NTOK) + n0;
#pragma unroll
    for (int p = 0; p < 4; p++) {
        int d = p * 16 + (t >> 4), c = t & 15;
        float4 v = *(const float4*)&src[d * NTOK + c * 4];
        Ls[d][c * 4 + 0] = v.x; Ls[d][c * 4 + 1] = v.y;
        Ls[d][c * 4 + 2] = v.z; Ls[d][c * 4 + 3] = v.w;
        if (ispf) {
            bf16x4 o = { (bf16_t)v.x, (bf16_t)v.y, (bf16_t)v.z, (bf16_t)v.w };
            *(bf16x4*)&pfC[((size_t)(b * PCH + d0 + d)) * NTOK + n0 + c * 4] = o;
        }
    }
    __syncthreads();
#pragma unroll
    for (int p = 0; p < 2; p++) {
        int n = p * 32 + (t >> 3), c = t & 7;
        bf16x8 o;
#pragma unroll
        for (int k = 0; k < 8; k++) o[k] = (bf16_t)Ls[c * 8 + k][n];
        if (ispf)
            *(bf16x8*)&pfT[((size_t)(b * NTOK + n0 + n)) * PCH + d0 + c * 8] = o;
        else
            *(bf16x8*)&imgT[((size_t)(b * NTOK + n0 + n)) * ICH + d0 + c * 8] = o;
    }
}

// ---------------------------------------------------------------------------
// K1: fc2 (MFMA) — ri[p][n] = sum_c w[p][c]*img[c][n] + bias[p]
// Also zeroes the zsum buffers (16384 floats) in its prologue.
// ---------------------------------------------------------------------------
__global__ __launch_bounds__(256) void fc2_mfma(const bf16_t* __restrict__ imgT,
                                                const float* __restrict__ w,
                                                const float* __restrict__ bias,
                                                bf16_t* __restrict__ riC,
                                                bf16_t* __restrict__ riT,
                                                float* __restrict__ zsums)
{
    const int t = threadIdx.x;
    if (blockIdx.y == 0 && blockIdx.z == 0)
        zsums[blockIdx.x * 256 + t] = 0.f;       // 64 blocks x 256 = 16384 floats

    const int n0 = blockIdx.x * 64, pbase = blockIdx.y * 64, b = blockIdx.z;
    const int lane = t & 63, wv = t >> 6, tx = lane & 15, q = lane >> 4;
    const int n = n0 + wv * 16 + tx;
    const bf16_t* trow = imgT + ((size_t)(b * NTOK + n)) * ICH;

    floatx4 acc[4];
#pragma unroll
    for (int ot = 0; ot < 4; ot++) acc[ot] = (floatx4){0.f, 0.f, 0.f, 0.f};

#pragma unroll
    for (int s = 0; s < 8; s++) {
        bf16x8 bf = *(const bf16x8*)&trow[s * 32 + q * 8];
#pragma unroll
        for (int ot = 0; ot < 4; ot++) {
            const float* wr = w + (size_t)(pbase + ot * 16 + tx) * ICH + s * 32 + q * 8;
            float4 x0 = *(const float4*)wr;
            float4 x1 = *(const float4*)(wr + 4);
            bf16x8 af;
            af[0] = (bf16_t)x0.x; af[1] = (bf16_t)x0.y; af[2] = (bf16_t)x0.z; af[3] = (bf16_t)x0.w;
            af[4] = (bf16_t)x1.x; af[5] = (bf16_t)x1.y; af[6] = (bf16_t)x1.z; af[7] = (bf16_t)x1.w;
            acc[ot] = __builtin_amdgcn_mfma_f32_16x16x32_bf16(af, bf, acc[ot], 0, 0, 0);
        }
    }

#pragma unroll
    for (int ot = 0; ot < 4; ot++) {
        bf16x4 tv;
#pragma unroll
        for (int r = 0; r < 4; r++) {
            const int p = pbase + ot * 16 + q * 4 + r;
            float v = acc[ot][r] + bias[p];
            tv[r] = (bf16_t)v;
            riC[((size_t)(b * PCH + p)) * NTOK + n] = (bf16_t)v;
        }
        *(bf16x4*)&riT[((size_t)(b * NTOK + n)) * PCH + pbase + ot * 16 + q * 4] = tv;
    }
}

// ---------------------------------------------------------------------------
// K2: stats v5 + XCD swizzle + fus-zero prologue (unchanged).
// ---------------------------------------------------------------------------
__global__ __launch_bounds__(256, 4) void stats_mfma(const bf16_t* __restrict__ pfT,
                                                     const bf16_t* __restrict__ riT,
                                                     float* __restrict__ zr,
                                                     float* __restrict__ zc,
                                                     float* __restrict__ fus)
{
    __shared__ bf16_t As[64 * LDK];
    __shared__ float zacc[1024];
    const int t = threadIdx.x;
    const int blk = blockIdx.x;

    { // zero fus: 512 blocks x 256 thr x 4 float4 = 2,097,152 floats exactly
        float4* f4 = (float4*)fus + ((size_t)blk * 256 + t) * 4;
        f4[0] = float4{0.f, 0.f, 0.f, 0.f};
        f4[1] = float4{0.f, 0.f, 0.f, 0.f};
        f4[2] = float4{0.f, 0.f, 0.f, 0.f};
        f4[3] = float4{0.f, 0.f, 0.f, 0.f};
    }

    const int g = blk & 7, slot = blk >> 3;      // XCD-aware decode
    const int b = g & 1, js = g >> 1;
    const bf16_t* At = pfT + (size_t)b * NTOK * PCH;
    const bf16_t* Bt = riT + (size_t)b * NTOK * PCH;
    float* zrow = zr + (size_t)b * NTOK;
    float* zcol = zc + (size_t)b * NTOK;
    const int lane = t & 63, w = t >> 6, tx = lane & 15, q = lane >> 4;
    const int i0 = slot * 64;
    const int jbase = js * 1024;
    const int sr = t >> 4, sc = t & 15;
    const bf16_t* Brow = Bt + (size_t)(jbase + w * 16 + tx) * PCH;

    bf16x8 bcur[4];
#pragma unroll
    for (int s = 0; s < 4; s++)
        bcur[s] = *(const bf16x8*)&Brow[s * 32 + q * 8];
#pragma unroll
    for (int p = 0; p < 4; p++) {
        int i = p * 16 + sr;
        *(uint4*)&As[i * LDK + sc * 8] = *(const uint4*)&At[((size_t)(i0 + i)) * PCH + sc * 8];
    }
    __syncthreads();
    bf16x8 af[4][4];
#pragma unroll
    for (int mt = 0; mt < 4; mt++)
#pragma unroll
        for (int s = 0; s < 4; s++)
            af[mt][s] = *(bf16x8*)&As[(mt * 16 + tx) * LDK + s * 32 + q * 8];

    float racc[4] = {0.f, 0.f, 0.f, 0.f};
    for (int jt = 0; jt < 16; jt++) {
        __builtin_amdgcn_s_barrier();            // pacing only
        floatx4 sacc[4];
#pragma unroll
        for (int mt = 0; mt < 4; mt++) {
            sacc[mt] = (floatx4){0.f, 0.f, 0.f, 0.f};
#pragma unroll
            for (int s = 0; s < 4; s++)
                sacc[mt] = __builtin_amdgcn_mfma_f32_16x16x32_bf16(bcur[s], af[mt][s], sacc[mt], 0, 0, 0);
        }
        if (jt < 15) {
            const bf16_t* bn = Brow + (size_t)(jt + 1) * 64 * PCH;
#pragma unroll
            for (int s = 0; s < 4; s++)
                bcur[s] = *(const bf16x8*)&bn[s * 32 + q * 8];
        }

        float ctmp[4] = {0.f, 0.f, 0.f, 0.f};
#pragma unroll
        for (int mt = 0; mt < 4; mt++)
#pragma unroll
            for (int r = 0; r < 4; r++) {
                float e = __expf(sacc[mt][r] * SCALEF);
                racc[mt] += e;
                ctmp[r]  += e;
            }
#pragma unroll
        for (int r = 0; r < 4; r++) {
            float v = ctmp[r];
            v += __shfl_xor(v, 1); v += __shfl_xor(v, 2);
            v += __shfl_xor(v, 4); v += __shfl_xor(v, 8);
            if (tx == 0) zacc[jt * 64 + w * 16 + q * 4 + r] = v;
        }
    }
#pragma unroll
    for (int mt = 0; mt < 4; mt++) {
        float v = racc[mt];
        v += __shfl_xor(v, 16);
        v += __shfl_xor(v, 32);
        if (q == 0) atomicAdd(&zrow[i0 + mt * 16 + tx], v);
    }
    __syncthreads();
#pragma unroll
    for (int k = 0; k < 4; k++)
        atomicAdd(&zcol[jbase + k * 256 + t], zacc[k * 256 + t]);
}

// ---------------------------------------------------------------------------
// K3: attn v3 — barrier-free wave-local pipeline (R1 structure), with the
// V-fragment stack-allocation bug fixed: R1 wrote vcur through
// ((bf16x4*)&vcur[c])[0/1], which takes the address of an ext_vector ->
// defeats SROA -> vcur became an alloca -> ~1 GB scratch round-trip
// (VGPR_Count fell to 104, WRITE_SIZE 32->131 MB, MfmaUtil 3.7%).
// v3 loads both 8B halves into named bf16x4 locals and combines with
// __builtin_shufflevector — whole-object assignment only, stays in VGPRs.
// ---------------------------------------------------------------------------
__global__ __launch_bounds__(256, 2) void attn_mfma(const bf16_t* __restrict__ pfT,
                                                    const bf16_t* __restrict__ riT,
                                                    const bf16_t* __restrict__ pfC,
                                                    const bf16_t* __restrict__ riC,
                                                    const float* __restrict__ zrsum,
                                                    const float* __restrict__ zcsum,
                                                    float* __restrict__ fus)
{
    __shared__ float Rs[4352];                 // 17408 B: bf16 As[64*LDK] aliased
    bf16_t* As = (bf16_t*)Rs;
    const int t = threadIdx.x;
    const int blk = blockIdx.x;
    const int g = blk & 7;                     // combo -> XCD
    const int slot = blk >> 3;                 // 0..63 i-slot
    const int b = g & 1, mode = (g >> 1) & 1, js = g >> 2;
    const bf16_t* At = (mode == 0 ? pfT : riT) + (size_t)b * NTOK * PCH;
    const bf16_t* Bt = (mode == 0 ? riT : pfT) + (size_t)b * NTOK * PCH;
    const bf16_t* Vc = (mode == 0 ? pfC : riC) + (size_t)b * PCH * NTOK;
    const float* wsum = (mode == 0 ? zcsum : zrsum) + (size_t)b * NTOK;
    const int lane = t & 63, w = t >> 6, tx = lane & 15, q = lane >> 4;
    const int h = w & 1, jh = w >> 1;
    const int i0 = slot * 64;
    const int jbase = js * 2048;
    const int sr = t >> 4, sc = t & 15;

    // stage A tile (rows i0..i0+63)
#pragma unroll
    for (int p = 0; p < 4; p++) {
        int i = p * 16 + sr;
        *(uint4*)&As[i * LDK + sc * 8] = *(const uint4*)&At[((size_t)(i0 + i)) * PCH + sc * 8];
    }
    __syncthreads();
    bf16x8 af[2][4];                           // this wave's 32 i-rows, held all kernel
#pragma unroll
    for (int mt = 0; mt < 2; mt++)
#pragma unroll
        for (int s = 0; s < 4; s++)
            af[mt][s] = *(bf16x8*)&As[(h * 32 + mt * 16 + tx) * LDK + s * 32 + q * 8];

    const bf16_t* Brow0 = Bt + (size_t)(jbase + jh * 32 + tx) * PCH;
    const bf16_t* Vrow  = Vc + (size_t)tx * NTOK + jbase + jh * 32 + q * 4;
    const float*  Wp    = wsum + jbase + jh * 32 + q * 4;

    floatx4 acc[2][8];                         // out[i=h*32+mt*16+q*4+r][d=c*16+tx]
#pragma unroll
    for (int mt = 0; mt < 2; mt++)
#pragma unroll
        for (int c = 0; c < 8; c++) acc[mt][c] = (floatx4){0.f, 0.f, 0.f, 0.f};

    // prologue loads (jt = 0)
    bf16x8 bcur[2][4];
#pragma unroll
    for (int jm = 0; jm < 2; jm++)
#pragma unroll
        for (int s = 0; s < 4; s++)
            bcur[jm][s] = *(const bf16x8*)&Brow0[(size_t)(jm * 16) * PCH + s * 32 + q * 8];
    bf16x8 vcur[8];
#pragma unroll
    for (int c = 0; c < 8; c++) {
        bf16x4 vlo = *(const bf16x4*)&Vrow[(size_t)(c * 16) * NTOK];
        bf16x4 vhi = *(const bf16x4*)&Vrow[(size_t)(c * 16) * NTOK + 16];
        vcur[c] = __builtin_shufflevector(vlo, vhi, 0, 1, 2, 3, 4, 5, 6, 7);
    }
    float4 wv0 = *(const float4*)&Wp[0];
    float4 wv1 = *(const float4*)&Wp[16];

#pragma unroll 1
    for (int jt = 0; jt < 32; jt++) {
        // QK: s[jm][mt], lane(q,tx) reg r = s[j = jt*64+jh*32+jm*16+q*4+r][i = i0+h*32+mt*16+tx]
        __builtin_amdgcn_s_setprio(1);
        floatx4 sx[2][2];
#pragma unroll
        for (int jm = 0; jm < 2; jm++)
#pragma unroll
            for (int mt = 0; mt < 2; mt++) {
                sx[jm][mt] = (floatx4){0.f, 0.f, 0.f, 0.f};
#pragma unroll
                for (int s = 0; s < 4; s++)
                    sx[jm][mt] = __builtin_amdgcn_mfma_f32_16x16x32_bf16(bcur[jm][s], af[mt][s], sx[jm][mt], 0, 0, 0);
            }
        __builtin_amdgcn_s_setprio(0);

        // reload B rows for next jt (WAR after QK; hides under exp+PV)
        if (jt < 31) {
            const bf16_t* bn = Brow0 + (size_t)((jt + 1) * 64) * PCH;
#pragma unroll
            for (int jm = 0; jm < 2; jm++)
#pragma unroll
                for (int s = 0; s < 4; s++)
                    bcur[jm][s] = *(const bf16x8*)&bn[(size_t)(jm * 16) * PCH + s * 32 + q * 8];
        }

        // exp + normalize, packed directly into PV A-frags (e<4: jm0, e>=4: jm1)
        float lz0[4] = { __builtin_amdgcn_logf(wv0.x), __builtin_amdgcn_logf(wv0.y),
                         __builtin_amdgcn_logf(wv0.z), __builtin_amdgcn_logf(wv0.w) };
        float lz1[4] = { __builtin_amdgcn_logf(wv1.x), __builtin_amdgcn_logf(wv1.y),
                         __builtin_amdgcn_logf(wv1.z), __builtin_amdgcn_logf(wv1.w) };
        bf16x8 ea[2];
#pragma unroll
        for (int mt = 0; mt < 2; mt++)
#pragma unroll
            for (int r = 0; r < 4; r++) {
                ea[mt][r]     = (bf16_t)__builtin_amdgcn_exp2f(sx[0][mt][r] * SCALE2 - lz0[r]);
                ea[mt][r + 4] = (bf16_t)__builtin_amdgcn_exp2f(sx[1][mt][r] * SCALE2 - lz1[r]);
            }
        if (jt < 31) {
            wv0 = *(const float4*)&Wp[(jt + 1) * 64];
            wv1 = *(const float4*)&Wp[(jt + 1) * 64 + 16];
        }

        // PV: 16 independent mfma, acc[mt][c] += E[i][j] * V[j][d]
        __builtin_amdgcn_s_setprio(1);
#pragma unroll
        for (int c = 0; c < 8; c++)
#pragma unroll
            for (int mt = 0; mt < 2; mt++)
                acc[mt][c] = __builtin_amdgcn_mfma_f32_16x16x32_bf16(ea[mt], vcur[c], acc[mt][c], 0, 0, 0);
        __builtin_amdgcn_s_setprio(0);

        // reload V frags for next jt (WAR after PV; hides under next QK+exp)
        if (jt < 31) {
            const bf16_t* vn = Vrow + (jt + 1) * 64;
#pragma unroll
            for (int c = 0; c < 8; c++) {
                bf16x4 vlo = *(const bf16x4*)&vn[(size_t)(c * 16) * NTOK];
                bf16x4 vhi = *(const bf16x4*)&vn[(size_t)(c * 16) * NTOK + 16];
                vcur[c] = __builtin_shufflevector(vlo, vhi, 0, 1, 2, 3, 4, 5, 6, 7);
            }
        }
    }

    // epilogue: cross-wave reduce (jh pairs) in LDS, then global atomics.
    __syncthreads();
#pragma unroll
    for (int half = 0; half < 2; half++) {
        for (int k = t; k < 64 * 65; k += 256) Rs[k] = 0.f;
        __syncthreads();
#pragma unroll
        for (int mt = 0; mt < 2; mt++)
#pragma unroll
            for (int c = 0; c < 4; c++)
#pragma unroll
                for (int r = 0; r < 4; r++)
                    atomicAdd(&Rs[(h * 32 + mt * 16 + q * 4 + r) * 65 + c * 16 + tx],
                              acc[mt][half * 4 + c][r]);
        __syncthreads();
        {
            const int il = t >> 2, d0 = (t & 3) * 16;
            float* fo = fus + ((size_t)(b * NTOK + i0 + il)) * 256 + mode * 128 + half * 64 + d0;
#pragma unroll
            for (int k = 0; k < 16; k++)
                atomicAdd(&fo[k], Rs[il * 65 + d0 + k]);
        }
        __syncthreads();
    }
}

// ---------------------------------------------------------------------------
// K4: conv (MFMA) — out[o][n] = relu(bn(sum_c cw[o][c]*fus[n][c] + cb))
// ---------------------------------------------------------------------------
__global__ __launch_bounds__(256) void conv_mfma(const float* __restrict__ fus,
                                                 const float* __restrict__ cw,
                                                 const float* __restrict__ cb,
                                                 const float* __restrict__ g,
                                                 const float* __restrict__ be,
                                                 const float* __restrict__ mu,
                                                 const float* __restrict__ var,
                                                 float* __restrict__ out)
{
    const int t = threadIdx.x;
    const int n0 = blockIdx.x * 64, obase = blockIdx.y * 64, b = blockIdx.z;
    const int lane = t & 63, wv = t >> 6, tx = lane & 15, q = lane >> 4;
    const int n = n0 + wv * 16 + tx;
    const float* frow = fus + ((size_t)(b * NTOK + n)) * 256;

    floatx4 acc[4];
#pragma unroll
    for (int ot = 0; ot < 4; ot++) acc[ot] = (floatx4){0.f, 0.f, 0.f, 0.f};

#pragma unroll
    for (int s = 0; s < 8; s++) {
        float4 f0 = *(const float4*)&frow[s * 32 + q * 8];
        float4 f1 = *(const float4*)&frow[s * 32 + q * 8 + 4];
        bf16x8 bf;
        bf[0] = (bf16_t)f0.x; bf[1] = (bf16_t)f0.y; bf[2] = (bf16_t)f0.z; bf[3] = (bf16_t)f0.w;
        bf[4] = (bf16_t)f1.x; bf[5] = (bf16_t)f1.y; bf[6] = (bf16_t)f1.z; bf[7] = (bf16_t)f1.w;
#pragma unroll
        for (int ot = 0; ot < 4; ot++) {
            const float* wr = cw + (size_t)(obase + ot * 16 + tx) * 256 + s * 32 + q * 8;
            float4 x0 = *(const float4*)wr;
            float4 x1 = *(const float4*)(wr + 4);
            bf16x8 af;
            af[0] = (bf16_t)x0.x; af[1] = (bf16_t)x0.y; af[2] = (bf16_t)x0.z; af[3] = (bf16_t)x0.w;
            af[4] = (bf16_t)x1.x; af[5] = (bf16_t)x1.y; af[6] = (bf16_t)x1.z; af[7] = (bf16_t)x1.w;
            acc[ot] = __builtin_amdgcn_mfma_f32_16x16x32_bf16(af, bf, acc[ot], 0, 0, 0);
        }
    }

#pragma unroll
    for (int ot = 0; ot < 4; ot++)
#pragma unroll
        for (int r = 0; r < 4; r++) {
            const int o = obase + ot * 16 + q * 4 + r;
            const float sc = g[o] * rsqrtf(var[o] + 1e-5f);
            const float b0 = be[o] + (cb[o] - mu[o]) * sc;
            float y = acc[ot][r] * sc + b0;
            out[((size_t)(b * OCH + o)) * NTOK + n] = fmaxf(y, 0.f);
        }
}

// ---------------------------------------------------------------------------
extern "C" void kernel_launch(void* const* d_in, const int* in_sizes, int n_in,
                              void* d_out, int out_size, void* d_ws, size_t ws_size,
                              hipStream_t stream)
{
    const float* pf   = (const float*)d_in[0];
    const float* img  = (const float*)d_in[1];
    const float* fc2w = (const float*)d_in[2];
    const float* fc2b = (const float*)d_in[3];
    const float* cw   = (const float*)d_in[4];
    const float* cb   = (const float*)d_in[5];
    const float* g    = (const float*)d_in[6];
    const float* be   = (const float*)d_in[7];
    const float* mu   = (const float*)d_in[8];
    const float* var  = (const float*)d_in[9];
    float* out = (float*)d_out;

    // ws layout: proven footprint (16,842,752 B). imgT aliases fus region
    // (dead after fc2; fus is zeroed inside stats which runs after fc2).
    float* fus   = (float*)d_ws;                              // 8 MB
    float* zrsum = fus + (size_t)NB * NTOK * 256;             // 32 KB
    float* zcsum = zrsum + NB * NTOK;                         // 32 KB (contiguous after zrsum)
    bf16_t* pfC = (bf16_t*)(zcsum + NB * NTOK);               // 2 MB
    bf16_t* pfT = pfC + (size_t)NB * PCH * NTOK;              // 2 MB
    bf16_t* riC = pfT + (size_t)NB * NTOK * PCH;              // 2 MB
    bf16_t* riT = riC + (size_t)NB * PCH * NTOK;              // 2 MB
    bf16_t* imgT = (bf16_t*)fus;                              // 4 MB alias

    pack_all  <<<dim3(64, 6, NB), 256, 0, stream>>>(pf, img, pfC, pfT, imgT);
    fc2_mfma  <<<dim3(64, 2, NB), 256, 0, stream>>>(imgT, fc2w, fc2b, riC, riT, zrsum);
    stats_mfma<<<dim3(512),       256, 0, stream>>>(pfT, riT, zrsum, zcsum, fus);
    attn_mfma <<<dim3(512),       256, 0, stream>>>(pfT, riT, pfC, riC, zrsum, zcsum, fus);
    conv_mfma <<<dim3(64, 2, NB), 256, 0, stream>>>(fus, cw, cb, g, be, mu, var, out);
}

// Round 3
// 336.556 us; speedup vs baseline: 1.4779x; 1.4779x over previous
//
#include <hip/hip_runtime.h>
#include <math.h>

// Problem constants
#define NTOK 4096
#define PCH  128
#define ICH  256
#define OCH  128
#define NB   2
#define SCALEF 0.08838834764831845f   // 1/sqrt(128)
#define SCALE2 0.12751743f            // SCALEF * log2(e)

typedef __bf16 bf16_t;
typedef __attribute__((ext_vector_type(8))) __bf16 bf16x8;
typedef __attribute__((ext_vector_type(4))) __bf16 bf16x4;
typedef __attribute__((ext_vector_type(4))) float floatx4;

#define LDK 136   // padded row length (bf16) for k=128 tiles

// ---------------------------------------------------------------------------
// K0: merged pack — y<2: pf -> pfC + pfT;  y>=2: img -> imgT (token-major)
// ---------------------------------------------------------------------------
__global__ __launch_bounds__(256) void pack_all(const float* __restrict__ pf,
                                                const float* __restrict__ img,
                                                bf16_t* __restrict__ pfC,
                                                bf16_t* __restrict__ pfT,
                                                bf16_t* __restrict__ imgT)
{
    __shared__ float Ls[64][65];
    const int t = threadIdx.x;
    const int n0 = blockIdx.x * 64, b = blockIdx.z;
    const bool ispf = blockIdx.y < 2;
    const int d0 = ispf ? blockIdx.y * 64 : (blockIdx.y - 2) * 64;
    const float* src = (ispf ? pf + ((size_t)(b * PCH + d0)) * NTOK
                             : img + ((size_t)(b * ICH + d0)) * NTOK) + n0;
#pragma unroll
    for (int p = 0; p < 4; p++) {
        int d = p * 16 + (t >> 4), c = t & 15;
        float4 v = *(const float4*)&src[d * NTOK + c * 4];
        Ls[d][c * 4 + 0] = v.x; Ls[d][c * 4 + 1] = v.y;
        Ls[d][c * 4 + 2] = v.z; Ls[d][c * 4 + 3] = v.w;
        if (ispf) {
            bf16x4 o = { (bf16_t)v.x, (bf16_t)v.y, (bf16_t)v.z, (bf16_t)v.w };
            *(bf16x4*)&pfC[((size_t)(b * PCH + d0 + d)) * NTOK + n0 + c * 4] = o;
        }
    }
    __syncthreads();
#pragma unroll
    for (int p = 0; p < 2; p++) {
        int n = p * 32 + (t >> 3), c = t & 7;
        bf16x8 o;
#pragma unroll
        for (int k = 0; k < 8; k++) o[k] = (bf16_t)Ls[c * 8 + k][n];
        if (ispf)
            *(bf16x8*)&pfT[((size_t)(b * NTOK + n0 + n)) * PCH + d0 + c * 8] = o;
        else
            *(bf16x8*)&imgT[((size_t)(b * NTOK + n0 + n)) * ICH + d0 + c * 8] = o;
    }
}

// ---------------------------------------------------------------------------
// K1: fc2 (MFMA) — ri[p][n] = sum_c w[p][c]*img[c][n] + bias[p]
// Also zeroes the zsum buffers (16384 floats) in its prologue.
// ---------------------------------------------------------------------------
__global__ __launch_bounds__(256) void fc2_mfma(const bf16_t* __restrict__ imgT,
                                                const float* __restrict__ w,
                                                const float* __restrict__ bias,
                                                bf16_t* __restrict__ riC,
                                                bf16_t* __restrict__ riT,
                                                float* __restrict__ zsums)
{
    const int t = threadIdx.x;
    if (blockIdx.y == 0 && blockIdx.z == 0)
        zsums[blockIdx.x * 256 + t] = 0.f;       // 64 blocks x 256 = 16384 floats

    const int n0 = blockIdx.x * 64, pbase = blockIdx.y * 64, b = blockIdx.z;
    const int lane = t & 63, wv = t >> 6, tx = lane & 15, q = lane >> 4;
    const int n = n0 + wv * 16 + tx;
    const bf16_t* trow = imgT + ((size_t)(b * NTOK + n)) * ICH;

    floatx4 acc[4];
#pragma unroll
    for (int ot = 0; ot < 4; ot++) acc[ot] = (floatx4){0.f, 0.f, 0.f, 0.f};

#pragma unroll
    for (int s = 0; s < 8; s++) {
        bf16x8 bf = *(const bf16x8*)&trow[s * 32 + q * 8];
#pragma unroll
        for (int ot = 0; ot < 4; ot++) {
            const float* wr = w + (size_t)(pbase + ot * 16 + tx) * ICH + s * 32 + q * 8;
            float4 x0 = *(const float4*)wr;
            float4 x1 = *(const float4*)(wr + 4);
            bf16x8 af;
            af[0] = (bf16_t)x0.x; af[1] = (bf16_t)x0.y; af[2] = (bf16_t)x0.z; af[3] = (bf16_t)x0.w;
            af[4] = (bf16_t)x1.x; af[5] = (bf16_t)x1.y; af[6] = (bf16_t)x1.z; af[7] = (bf16_t)x1.w;
            acc[ot] = __builtin_amdgcn_mfma_f32_16x16x32_bf16(af, bf, acc[ot], 0, 0, 0);
        }
    }

#pragma unroll
    for (int ot = 0; ot < 4; ot++) {
        bf16x4 tv;
#pragma unroll
        for (int r = 0; r < 4; r++) {
            const int p = pbase + ot * 16 + q * 4 + r;
            float v = acc[ot][r] + bias[p];
            tv[r] = (bf16_t)v;
            riC[((size_t)(b * PCH + p)) * NTOK + n] = (bf16_t)v;
        }
        *(bf16x4*)&riT[((size_t)(b * NTOK + n)) * PCH + pbase + ot * 16 + q * 4] = tv;
    }
}

// ---------------------------------------------------------------------------
// K2: stats v5 + XCD swizzle + fus-zero prologue (unchanged).
// ---------------------------------------------------------------------------
__global__ __launch_bounds__(256, 4) void stats_mfma(const bf16_t* __restrict__ pfT,
                                                     const bf16_t* __restrict__ riT,
                                                     float* __restrict__ zr,
                                                     float* __restrict__ zc,
                                                     float* __restrict__ fus)
{
    __shared__ bf16_t As[64 * LDK];
    __shared__ float zacc[1024];
    const int t = threadIdx.x;
    const int blk = blockIdx.x;

    { // zero fus: 512 blocks x 256 thr x 4 float4 = 2,097,152 floats exactly
        float4* f4 = (float4*)fus + ((size_t)blk * 256 + t) * 4;
        f4[0] = float4{0.f, 0.f, 0.f, 0.f};
        f4[1] = float4{0.f, 0.f, 0.f, 0.f};
        f4[2] = float4{0.f, 0.f, 0.f, 0.f};
        f4[3] = float4{0.f, 0.f, 0.f, 0.f};
    }

    const int g = blk & 7, slot = blk >> 3;      // XCD-aware decode
    const int b = g & 1, js = g >> 1;
    const bf16_t* At = pfT + (size_t)b * NTOK * PCH;
    const bf16_t* Bt = riT + (size_t)b * NTOK * PCH;
    float* zrow = zr + (size_t)b * NTOK;
    float* zcol = zc + (size_t)b * NTOK;
    const int lane = t & 63, w = t >> 6, tx = lane & 15, q = lane >> 4;
    const int i0 = slot * 64;
    const int jbase = js * 1024;
    const int sr = t >> 4, sc = t & 15;
    const bf16_t* Brow = Bt + (size_t)(jbase + w * 16 + tx) * PCH;

    bf16x8 bcur[4];
#pragma unroll
    for (int s = 0; s < 4; s++)
        bcur[s] = *(const bf16x8*)&Brow[s * 32 + q * 8];
#pragma unroll
    for (int p = 0; p < 4; p++) {
        int i = p * 16 + sr;
        *(uint4*)&As[i * LDK + sc * 8] = *(const uint4*)&At[((size_t)(i0 + i)) * PCH + sc * 8];
    }
    __syncthreads();
    bf16x8 af[4][4];
#pragma unroll
    for (int mt = 0; mt < 4; mt++)
#pragma unroll
        for (int s = 0; s < 4; s++)
            af[mt][s] = *(bf16x8*)&As[(mt * 16 + tx) * LDK + s * 32 + q * 8];

    float racc[4] = {0.f, 0.f, 0.f, 0.f};
    for (int jt = 0; jt < 16; jt++) {
        __builtin_amdgcn_s_barrier();            // pacing only
        floatx4 sacc[4];
#pragma unroll
        for (int mt = 0; mt < 4; mt++) {
            sacc[mt] = (floatx4){0.f, 0.f, 0.f, 0.f};
#pragma unroll
            for (int s = 0; s < 4; s++)
                sacc[mt] = __builtin_amdgcn_mfma_f32_16x16x32_bf16(bcur[s], af[mt][s], sacc[mt], 0, 0, 0);
        }
        if (jt < 15) {
            const bf16_t* bn = Brow + (size_t)(jt + 1) * 64 * PCH;
#pragma unroll
            for (int s = 0; s < 4; s++)
                bcur[s] = *(const bf16x8*)&bn[s * 32 + q * 8];
        }

        float ctmp[4] = {0.f, 0.f, 0.f, 0.f};
#pragma unroll
        for (int mt = 0; mt < 4; mt++)
#pragma unroll
            for (int r = 0; r < 4; r++) {
                float e = __expf(sacc[mt][r] * SCALEF);
                racc[mt] += e;
                ctmp[r]  += e;
            }
#pragma unroll
        for (int r = 0; r < 4; r++) {
            float v = ctmp[r];
            v += __shfl_xor(v, 1); v += __shfl_xor(v, 2);
            v += __shfl_xor(v, 4); v += __shfl_xor(v, 8);
            if (tx == 0) zacc[jt * 64 + w * 16 + q * 4 + r] = v;
        }
    }
#pragma unroll
    for (int mt = 0; mt < 4; mt++) {
        float v = racc[mt];
        v += __shfl_xor(v, 16);
        v += __shfl_xor(v, 32);
        if (q == 0) atomicAdd(&zrow[i0 + mt * 16 + tx], v);
    }
    __syncthreads();
#pragma unroll
    for (int k = 0; k < 4; k++)
        atomicAdd(&zcol[jbase + k * 256 + t], zacc[k * 256 + t]);
}

// ---------------------------------------------------------------------------
// K3: attn v4 — barrier-free wave-local pipeline, R2 post-mortem fixes:
// (a) COALESCED epilogue atomics. R1/R2's epilogue had 64 lanes hitting 64
//     distinct lines per atomic instruction -> one 32B sector RMW per lane:
//     4.2M atomics x 32B = 134 MB WRITE_SIZE (measured exactly), ~320 us of
//     memory-side atomic drain. v4: wave w stores rows w*16..+15 with
//     lane=d -> 64 consecutive floats per instruction (16 lanes/line, the
//     proven R0 pattern that measured 33.5 MB for 8.4M atomics).
// (b) sched_barrier(0) after each prefetch block so the scheduler cannot
//     sink next-tile B/V/wsum loads into their consumers (VGPR 104 in
//     R1/R2 says they were sunk; latency fully exposed).
// ---------------------------------------------------------------------------
__global__ __launch_bounds__(256, 2) void attn_mfma(const bf16_t* __restrict__ pfT,
                                                    const bf16_t* __restrict__ riT,
                                                    const bf16_t* __restrict__ pfC,
                                                    const bf16_t* __restrict__ riC,
                                                    const float* __restrict__ zrsum,
                                                    const float* __restrict__ zcsum,
                                                    float* __restrict__ fus)
{
    __shared__ float Rs[4352];                 // 17408 B: bf16 As[64*LDK] aliased
    bf16_t* As = (bf16_t*)Rs;
    const int t = threadIdx.x;
    const int blk = blockIdx.x;
    const int g = blk & 7;                     // combo -> XCD
    const int slot = blk >> 3;                 // 0..63 i-slot
    const int b = g & 1, mode = (g >> 1) & 1, js = g >> 2;
    const bf16_t* At = (mode == 0 ? pfT : riT) + (size_t)b * NTOK * PCH;
    const bf16_t* Bt = (mode == 0 ? riT : pfT) + (size_t)b * NTOK * PCH;
    const bf16_t* Vc = (mode == 0 ? pfC : riC) + (size_t)b * PCH * NTOK;
    const float* wsum = (mode == 0 ? zcsum : zrsum) + (size_t)b * NTOK;
    const int lane = t & 63, w = t >> 6, tx = lane & 15, q = lane >> 4;
    const int h = w & 1, jh = w >> 1;
    const int i0 = slot * 64;
    const int jbase = js * 2048;
    const int sr = t >> 4, sc = t & 15;

    // stage A tile (rows i0..i0+63)
#pragma unroll
    for (int p = 0; p < 4; p++) {
        int i = p * 16 + sr;
        *(uint4*)&As[i * LDK + sc * 8] = *(const uint4*)&At[((size_t)(i0 + i)) * PCH + sc * 8];
    }
    __syncthreads();
    bf16x8 af[2][4];                           // this wave's 32 i-rows, held all kernel
#pragma unroll
    for (int mt = 0; mt < 2; mt++)
#pragma unroll
        for (int s = 0; s < 4; s++)
            af[mt][s] = *(bf16x8*)&As[(h * 32 + mt * 16 + tx) * LDK + s * 32 + q * 8];

    const bf16_t* Brow0 = Bt + (size_t)(jbase + jh * 32 + tx) * PCH;
    const bf16_t* Vrow  = Vc + (size_t)tx * NTOK + jbase + jh * 32 + q * 4;
    const float*  Wp    = wsum + jbase + jh * 32 + q * 4;

    floatx4 acc[2][8];                         // out[i=h*32+mt*16+q*4+r][d=c*16+tx]
#pragma unroll
    for (int mt = 0; mt < 2; mt++)
#pragma unroll
        for (int c = 0; c < 8; c++) acc[mt][c] = (floatx4){0.f, 0.f, 0.f, 0.f};

    // prologue loads (jt = 0)
    bf16x8 bcur[2][4];
#pragma unroll
    for (int jm = 0; jm < 2; jm++)
#pragma unroll
        for (int s = 0; s < 4; s++)
            bcur[jm][s] = *(const bf16x8*)&Brow0[(size_t)(jm * 16) * PCH + s * 32 + q * 8];
    bf16x8 vcur[8];
#pragma unroll
    for (int c = 0; c < 8; c++) {
        bf16x4 vlo = *(const bf16x4*)&Vrow[(size_t)(c * 16) * NTOK];
        bf16x4 vhi = *(const bf16x4*)&Vrow[(size_t)(c * 16) * NTOK + 16];
        vcur[c] = __builtin_shufflevector(vlo, vhi, 0, 1, 2, 3, 4, 5, 6, 7);
    }
    float4 wv0 = *(const float4*)&Wp[0];
    float4 wv1 = *(const float4*)&Wp[16];
    float4 wn0 = wv0, wn1 = wv1;

#pragma unroll 1
    for (int jt = 0; jt < 32; jt++) {
        // QK: lane(q,tx) reg r = s[j = jt*64+jh*32+jm*16+q*4+r][i = i0+h*32+mt*16+tx]
        __builtin_amdgcn_s_setprio(1);
        floatx4 sx[2][2];
#pragma unroll
        for (int jm = 0; jm < 2; jm++)
#pragma unroll
            for (int mt = 0; mt < 2; mt++) {
                sx[jm][mt] = (floatx4){0.f, 0.f, 0.f, 0.f};
#pragma unroll
                for (int s = 0; s < 4; s++)
                    sx[jm][mt] = __builtin_amdgcn_mfma_f32_16x16x32_bf16(bcur[jm][s], af[mt][s], sx[jm][mt], 0, 0, 0);
            }
        __builtin_amdgcn_s_setprio(0);

        // prefetch B rows + wsum for jt+1; pin issue point with sched_barrier
        if (jt < 31) {
            const bf16_t* bn = Brow0 + (size_t)((jt + 1) * 64) * PCH;
#pragma unroll
            for (int jm = 0; jm < 2; jm++)
#pragma unroll
                for (int s = 0; s < 4; s++)
                    bcur[jm][s] = *(const bf16x8*)&bn[(size_t)(jm * 16) * PCH + s * 32 + q * 8];
            wn0 = *(const float4*)&Wp[(jt + 1) * 64];
            wn1 = *(const float4*)&Wp[(jt + 1) * 64 + 16];
        }
        __builtin_amdgcn_sched_barrier(0);

        // exp + normalize, packed directly into PV A-frags (e<4: jm0, e>=4: jm1)
        float lz00 = __builtin_amdgcn_logf(wv0.x), lz01 = __builtin_amdgcn_logf(wv0.y);
        float lz02 = __builtin_amdgcn_logf(wv0.z), lz03 = __builtin_amdgcn_logf(wv0.w);
        float lz10 = __builtin_amdgcn_logf(wv1.x), lz11 = __builtin_amdgcn_logf(wv1.y);
        float lz12 = __builtin_amdgcn_logf(wv1.z), lz13 = __builtin_amdgcn_logf(wv1.w);
        bf16x8 ea0 = {
            (bf16_t)__builtin_amdgcn_exp2f(sx[0][0][0] * SCALE2 - lz00),
            (bf16_t)__builtin_amdgcn_exp2f(sx[0][0][1] * SCALE2 - lz01),
            (bf16_t)__builtin_amdgcn_exp2f(sx[0][0][2] * SCALE2 - lz02),
            (bf16_t)__builtin_amdgcn_exp2f(sx[0][0][3] * SCALE2 - lz03),
            (bf16_t)__builtin_amdgcn_exp2f(sx[1][0][0] * SCALE2 - lz10),
            (bf16_t)__builtin_amdgcn_exp2f(sx[1][0][1] * SCALE2 - lz11),
            (bf16_t)__builtin_amdgcn_exp2f(sx[1][0][2] * SCALE2 - lz12),
            (bf16_t)__builtin_amdgcn_exp2f(sx[1][0][3] * SCALE2 - lz13) };
        bf16x8 ea1 = {
            (bf16_t)__builtin_amdgcn_exp2f(sx[0][1][0] * SCALE2 - lz00),
            (bf16_t)__builtin_amdgcn_exp2f(sx[0][1][1] * SCALE2 - lz01),
            (bf16_t)__builtin_amdgcn_exp2f(sx[0][1][2] * SCALE2 - lz02),
            (bf16_t)__builtin_amdgcn_exp2f(sx[0][1][3] * SCALE2 - lz03),
            (bf16_t)__builtin_amdgcn_exp2f(sx[1][1][0] * SCALE2 - lz10),
            (bf16_t)__builtin_amdgcn_exp2f(sx[1][1][1] * SCALE2 - lz11),
            (bf16_t)__builtin_amdgcn_exp2f(sx[1][1][2] * SCALE2 - lz12),
            (bf16_t)__builtin_amdgcn_exp2f(sx[1][1][3] * SCALE2 - lz13) };

        // PV: 16 independent mfma, acc[mt][c] += E[i][j] * V[j][d]
        __builtin_amdgcn_s_setprio(1);
#pragma unroll
        for (int c = 0; c < 8; c++) {
            acc[0][c] = __builtin_amdgcn_mfma_f32_16x16x32_bf16(ea0, vcur[c], acc[0][c], 0, 0, 0);
            acc[1][c] = __builtin_amdgcn_mfma_f32_16x16x32_bf16(ea1, vcur[c], acc[1][c], 0, 0, 0);
        }
        __builtin_amdgcn_s_setprio(0);

        // prefetch V frags for jt+1; rotate wsum; pin with sched_barrier
        if (jt < 31) {
            const bf16_t* vn = Vrow + (jt + 1) * 64;
#pragma unroll
            for (int c = 0; c < 8; c++) {
                bf16x4 vlo = *(const bf16x4*)&vn[(size_t)(c * 16) * NTOK];
                bf16x4 vhi = *(const bf16x4*)&vn[(size_t)(c * 16) * NTOK + 16];
                vcur[c] = __builtin_shufflevector(vlo, vhi, 0, 1, 2, 3, 4, 5, 6, 7);
            }
            wv0 = wn0; wv1 = wn1;
        }
        __builtin_amdgcn_sched_barrier(0);
    }

    // epilogue: cross-wave reduce (jh pairs) in LDS, then COALESCED atomics:
    // wave w owns rows w*16..w*16+15, lane = d (64 consecutive floats/instr).
    __syncthreads();
#pragma unroll
    for (int half = 0; half < 2; half++) {
        for (int k = t; k < 64 * 65; k += 256) Rs[k] = 0.f;
        __syncthreads();
#pragma unroll
        for (int mt = 0; mt < 2; mt++)
#pragma unroll
            for (int c = 0; c < 4; c++)
#pragma unroll
                for (int r = 0; r < 4; r++)
                    atomicAdd(&Rs[(h * 32 + mt * 16 + q * 4 + r) * 65 + c * 16 + tx],
                              acc[mt][half * 4 + c][r]);
        __syncthreads();
        {
            float* fo = fus + ((size_t)(b * NTOK + i0)) * 256 + mode * 128 + half * 64;
#pragma unroll
            for (int k = 0; k < 16; k++) {
                const int row = w * 16 + k;
                atomicAdd(&fo[(size_t)row * 256 + lane], Rs[row * 65 + lane]);
            }
        }
        __syncthreads();
    }
}

// ---------------------------------------------------------------------------
// K4: conv (MFMA) — out[o][n] = relu(bn(sum_c cw[o][c]*fus[n][c] + cb))
// ---------------------------------------------------------------------------
__global__ __launch_bounds__(256) void conv_mfma(const float* __restrict__ fus,
                                                 const float* __restrict__ cw,
                                                 const float* __restrict__ cb,
                                                 const float* __restrict__ g,
                                                 const float* __restrict__ be,
                                                 const float* __restrict__ mu,
                                                 const float* __restrict__ var,
                                                 float* __restrict__ out)
{
    const int t = threadIdx.x;
    const int n0 = blockIdx.x * 64, obase = blockIdx.y * 64, b = blockIdx.z;
    const int lane = t & 63, wv = t >> 6, tx = lane & 15, q = lane >> 4;
    const int n = n0 + wv * 16 + tx;
    const float* frow = fus + ((size_t)(b * NTOK + n)) * 256;

    floatx4 acc[4];
#pragma unroll
    for (int ot = 0; ot < 4; ot++) acc[ot] = (floatx4){0.f, 0.f, 0.f, 0.f};

#pragma unroll
    for (int s = 0; s < 8; s++) {
        float4 f0 = *(const float4*)&frow[s * 32 + q * 8];
        float4 f1 = *(const float4*)&frow[s * 32 + q * 8 + 4];
        bf16x8 bf;
        bf[0] = (bf16_t)f0.x; bf[1] = (bf16_t)f0.y; bf[2] = (bf16_t)f0.z; bf[3] = (bf16_t)f0.w;
        bf[4] = (bf16_t)f1.x; bf[5] = (bf16_t)f1.y; bf[6] = (bf16_t)f1.z; bf[7] = (bf16_t)f1.w;
#pragma unroll
        for (int ot = 0; ot < 4; ot++) {
            const float* wr = cw + (size_t)(obase + ot * 16 + tx) * 256 + s * 32 + q * 8;
            float4 x0 = *(const float4*)wr;
            float4 x1 = *(const float4*)(wr + 4);
            bf16x8 af;
            af[0] = (bf16_t)x0.x; af[1] = (bf16_t)x0.y; af[2] = (bf16_t)x0.z; af[3] = (bf16_t)x0.w;
            af[4] = (bf16_t)x1.x; af[5] = (bf16_t)x1.y; af[6] = (bf16_t)x1.z; af[7] = (bf16_t)x1.w;
            acc[ot] = __builtin_amdgcn_mfma_f32_16x16x32_bf16(af, bf, acc[ot], 0, 0, 0);
        }
    }

#pragma unroll
    for (int ot = 0; ot < 4; ot++)
#pragma unroll
        for (int r = 0; r < 4; r++) {
            const int o = obase + ot * 16 + q * 4 + r;
            const float sc = g[o] * rsqrtf(var[o] + 1e-5f);
            const float b0 = be[o] + (cb[o] - mu[o]) * sc;
            float y = acc[ot][r] * sc + b0;
            out[((size_t)(b * OCH + o)) * NTOK + n] = fmaxf(y, 0.f);
        }
}

// ---------------------------------------------------------------------------
extern "C" void kernel_launch(void* const* d_in, const int* in_sizes, int n_in,
                              void* d_out, int out_size, void* d_ws, size_t ws_size,
                              hipStream_t stream)
{
    const float* pf   = (const float*)d_in[0];
    const float* img  = (const float*)d_in[1];
    const float* fc2w = (const float*)d_in[2];
    const float* fc2b = (const float*)d_in[3];
    const float* cw   = (const float*)d_in[4];
    const float* cb   = (const float*)d_in[5];
    const float* g    = (const float*)d_in[6];
    const float* be   = (const float*)d_in[7];
    const float* mu   = (const float*)d_in[8];
    const float* var  = (const float*)d_in[9];
    float* out = (float*)d_out;

    // ws layout: proven footprint (16,842,752 B). imgT aliases fus region
    // (dead after fc2; fus is zeroed inside stats which runs after fc2).
    float* fus   = (float*)d_ws;                              // 8 MB
    float* zrsum = fus + (size_t)NB * NTOK * 256;             // 32 KB
    float* zcsum = zrsum + NB * NTOK;                         // 32 KB (contiguous after zrsum)
    bf16_t* pfC = (bf16_t*)(zcsum + NB * NTOK);               // 2 MB
    bf16_t* pfT = pfC + (size_t)NB * PCH * NTOK;              // 2 MB
    bf16_t* riC = pfT + (size_t)NB * NTOK * PCH;              // 2 MB
    bf16_t* riT = riC + (size_t)NB * PCH * NTOK;              // 2 MB
    bf16_t* imgT = (bf16_t*)fus;                              // 4 MB alias

    pack_all  <<<dim3(64, 6, NB), 256, 0, stream>>>(pf, img, pfC, pfT, imgT);
    fc2_mfma  <<<dim3(64, 2, NB), 256, 0, stream>>>(imgT, fc2w, fc2b, riC, riT, zrsum);
    stats_mfma<<<dim3(512),       256, 0, stream>>>(pfT, riT, zrsum, zcsum, fus);
    attn_mfma <<<dim3(512),       256, 0, stream>>>(pfT, riT, pfC, riC, zrsum, zcsum, fus);
    conv_mfma <<<dim3(64, 2, NB), 256, 0, stream>>>(fus, cw, cb, g, be, mu, var, out);
}

// Round 4
// 330.977 us; speedup vs baseline: 1.5028x; 1.0169x over previous
//
#include <hip/hip_runtime.h>
#include <math.h>

// Problem constants
#define NTOK 4096
#define PCH  128
#define ICH  256
#define OCH  128
#define NB   2
#define SCALEF 0.08838834764831845f   // 1/sqrt(128)
#define SCALE2 0.12751743f            // SCALEF * log2(e)

typedef __bf16 bf16_t;
typedef __attribute__((ext_vector_type(8))) __bf16 bf16x8;
typedef __attribute__((ext_vector_type(4))) __bf16 bf16x4;
typedef __attribute__((ext_vector_type(4))) float floatx4;

#define LDK 136   // padded row length (bf16) for k=128 tiles

// ---------------------------------------------------------------------------
// K0: merged pack — y<2: pf -> pfC + pfT;  y>=2: img -> imgT (token-major)
// ---------------------------------------------------------------------------
__global__ __launch_bounds__(256) void pack_all(const float* __restrict__ pf,
                                                const float* __restrict__ img,
                                                bf16_t* __restrict__ pfC,
                                                bf16_t* __restrict__ pfT,
                                                bf16_t* __restrict__ imgT)
{
    __shared__ float Ls[64][65];
    const int t = threadIdx.x;
    const int n0 = blockIdx.x * 64, b = blockIdx.z;
    const bool ispf = blockIdx.y < 2;
    const int d0 = ispf ? blockIdx.y * 64 : (blockIdx.y - 2) * 64;
    const float* src = (ispf ? pf + ((size_t)(b * PCH + d0)) * NTOK
                             : img + ((size_t)(b * ICH + d0)) * NTOK) + n0;
#pragma unroll
    for (int p = 0; p < 4; p++) {
        int d = p * 16 + (t >> 4), c = t & 15;
        float4 v = *(const float4*)&src[d * NTOK + c * 4];
        Ls[d][c * 4 + 0] = v.x; Ls[d][c * 4 + 1] = v.y;
        Ls[d][c * 4 + 2] = v.z; Ls[d][c * 4 + 3] = v.w;
        if (ispf) {
            bf16x4 o = { (bf16_t)v.x, (bf16_t)v.y, (bf16_t)v.z, (bf16_t)v.w };
            *(bf16x4*)&pfC[((size_t)(b * PCH + d0 + d)) * NTOK + n0 + c * 4] = o;
        }
    }
    __syncthreads();
#pragma unroll
    for (int p = 0; p < 2; p++) {
        int n = p * 32 + (t >> 3), c = t & 7;
        bf16x8 o;
#pragma unroll
        for (int k = 0; k < 8; k++) o[k] = (bf16_t)Ls[c * 8 + k][n];
        if (ispf)
            *(bf16x8*)&pfT[((size_t)(b * NTOK + n0 + n)) * PCH + d0 + c * 8] = o;
        else
            *(bf16x8*)&imgT[((size_t)(b * NTOK + n0 + n)) * ICH + d0 + c * 8] = o;
    }
}

// ---------------------------------------------------------------------------
// K1: fc2 (MFMA) — ri[p][n] = sum_c w[p][c]*img[c][n] + bias[p]
// Also zeroes the zsum buffers (16384 floats) in its prologue.
// ---------------------------------------------------------------------------
__global__ __launch_bounds__(256) void fc2_mfma(const bf16_t* __restrict__ imgT,
                                                const float* __restrict__ w,
                                                const float* __restrict__ bias,
                                                bf16_t* __restrict__ riC,
                                                bf16_t* __restrict__ riT,
                                                float* __restrict__ zsums)
{
    const int t = threadIdx.x;
    if (blockIdx.y == 0 && blockIdx.z == 0)
        zsums[blockIdx.x * 256 + t] = 0.f;       // 64 blocks x 256 = 16384 floats

    const int n0 = blockIdx.x * 64, pbase = blockIdx.y * 64, b = blockIdx.z;
    const int lane = t & 63, wv = t >> 6, tx = lane & 15, q = lane >> 4;
    const int n = n0 + wv * 16 + tx;
    const bf16_t* trow = imgT + ((size_t)(b * NTOK + n)) * ICH;

    floatx4 acc[4];
#pragma unroll
    for (int ot = 0; ot < 4; ot++) acc[ot] = (floatx4){0.f, 0.f, 0.f, 0.f};

#pragma unroll
    for (int s = 0; s < 8; s++) {
        bf16x8 bf = *(const bf16x8*)&trow[s * 32 + q * 8];
#pragma unroll
        for (int ot = 0; ot < 4; ot++) {
            const float* wr = w + (size_t)(pbase + ot * 16 + tx) * ICH + s * 32 + q * 8;
            float4 x0 = *(const float4*)wr;
            float4 x1 = *(const float4*)(wr + 4);
            bf16x8 af;
            af[0] = (bf16_t)x0.x; af[1] = (bf16_t)x0.y; af[2] = (bf16_t)x0.z; af[3] = (bf16_t)x0.w;
            af[4] = (bf16_t)x1.x; af[5] = (bf16_t)x1.y; af[6] = (bf16_t)x1.z; af[7] = (bf16_t)x1.w;
            acc[ot] = __builtin_amdgcn_mfma_f32_16x16x32_bf16(af, bf, acc[ot], 0, 0, 0);
        }
    }

#pragma unroll
    for (int ot = 0; ot < 4; ot++) {
        bf16x4 tv;
#pragma unroll
        for (int r = 0; r < 4; r++) {
            const int p = pbase + ot * 16 + q * 4 + r;
            float v = acc[ot][r] + bias[p];
            tv[r] = (bf16_t)v;
            riC[((size_t)(b * PCH + p)) * NTOK + n] = (bf16_t)v;
        }
        *(bf16x4*)&riT[((size_t)(b * NTOK + n)) * PCH + pbase + ot * 16 + q * 4] = tv;
    }
}

// ---------------------------------------------------------------------------
// K2: stats v5 + XCD swizzle + fus-zero prologue (unchanged).
// ---------------------------------------------------------------------------
__global__ __launch_bounds__(256, 4) void stats_mfma(const bf16_t* __restrict__ pfT,
                                                     const bf16_t* __restrict__ riT,
                                                     float* __restrict__ zr,
                                                     float* __restrict__ zc,
                                                     float* __restrict__ fus)
{
    __shared__ bf16_t As[64 * LDK];
    __shared__ float zacc[1024];
    const int t = threadIdx.x;
    const int blk = blockIdx.x;

    { // zero fus: 512 blocks x 256 thr x 4 float4 = 2,097,152 floats exactly
        float4* f4 = (float4*)fus + ((size_t)blk * 256 + t) * 4;
        f4[0] = float4{0.f, 0.f, 0.f, 0.f};
        f4[1] = float4{0.f, 0.f, 0.f, 0.f};
        f4[2] = float4{0.f, 0.f, 0.f, 0.f};
        f4[3] = float4{0.f, 0.f, 0.f, 0.f};
    }

    const int g = blk & 7, slot = blk >> 3;      // XCD-aware decode
    const int b = g & 1, js = g >> 1;
    const bf16_t* At = pfT + (size_t)b * NTOK * PCH;
    const bf16_t* Bt = riT + (size_t)b * NTOK * PCH;
    float* zrow = zr + (size_t)b * NTOK;
    float* zcol = zc + (size_t)b * NTOK;
    const int lane = t & 63, w = t >> 6, tx = lane & 15, q = lane >> 4;
    const int i0 = slot * 64;
    const int jbase = js * 1024;
    const int sr = t >> 4, sc = t & 15;
    const bf16_t* Brow = Bt + (size_t)(jbase + w * 16 + tx) * PCH;

    bf16x8 bcur[4];
#pragma unroll
    for (int s = 0; s < 4; s++)
        bcur[s] = *(const bf16x8*)&Brow[s * 32 + q * 8];
#pragma unroll
    for (int p = 0; p < 4; p++) {
        int i = p * 16 + sr;
        *(uint4*)&As[i * LDK + sc * 8] = *(const uint4*)&At[((size_t)(i0 + i)) * PCH + sc * 8];
    }
    __syncthreads();
    bf16x8 af[4][4];
#pragma unroll
    for (int mt = 0; mt < 4; mt++)
#pragma unroll
        for (int s = 0; s < 4; s++)
            af[mt][s] = *(bf16x8*)&As[(mt * 16 + tx) * LDK + s * 32 + q * 8];

    float racc[4] = {0.f, 0.f, 0.f, 0.f};
    for (int jt = 0; jt < 16; jt++) {
        __builtin_amdgcn_s_barrier();            // pacing only
        floatx4 sacc[4];
#pragma unroll
        for (int mt = 0; mt < 4; mt++) {
            sacc[mt] = (floatx4){0.f, 0.f, 0.f, 0.f};
#pragma unroll
            for (int s = 0; s < 4; s++)
                sacc[mt] = __builtin_amdgcn_mfma_f32_16x16x32_bf16(bcur[s], af[mt][s], sacc[mt], 0, 0, 0);
        }
        if (jt < 15) {
            const bf16_t* bn = Brow + (size_t)(jt + 1) * 64 * PCH;
#pragma unroll
            for (int s = 0; s < 4; s++)
                bcur[s] = *(const bf16x8*)&bn[s * 32 + q * 8];
        }

        float ctmp[4] = {0.f, 0.f, 0.f, 0.f};
#pragma unroll
        for (int mt = 0; mt < 4; mt++)
#pragma unroll
            for (int r = 0; r < 4; r++) {
                float e = __expf(sacc[mt][r] * SCALEF);
                racc[mt] += e;
                ctmp[r]  += e;
            }
#pragma unroll
        for (int r = 0; r < 4; r++) {
            float v = ctmp[r];
            v += __shfl_xor(v, 1); v += __shfl_xor(v, 2);
            v += __shfl_xor(v, 4); v += __shfl_xor(v, 8);
            if (tx == 0) zacc[jt * 64 + w * 16 + q * 4 + r] = v;
        }
    }
#pragma unroll
    for (int mt = 0; mt < 4; mt++) {
        float v = racc[mt];
        v += __shfl_xor(v, 16);
        v += __shfl_xor(v, 32);
        if (q == 0) atomicAdd(&zrow[i0 + mt * 16 + tx], v);
    }
    __syncthreads();
#pragma unroll
    for (int k = 0; k < 4; k++)
        atomicAdd(&zcol[jbase + k * 256 + t], zacc[k * 256 + t]);
}

// ---------------------------------------------------------------------------
// K3: attn v5 — same register dataflow as v4 (verified correct: swapped-QK
// C-frag == PV A-frag identity, in-register exp2-normalized softmax,
// coalesced atomic epilogue), but B and V now staged cooperatively in LDS.
//
// R3 diagnosis: v4 fed MFMAs from per-lane global gathers: ~390 strided
// L2 line-transactions/wave/jt (V at 8KB row stride, 32B useful/line; B
// fetched twice per block by the two h-waves) -> ~25M L2 transactions,
// MfmaUtil 6.5%, dur 205us. v5 stages the 16KB B tile (contiguous) and
// 16KB V tile once per block per jt with fully-coalesced 16B/lane loads
// (full 64B lines, ~6x fewer transactions), then waves read fragments
// from padded LDS (B rows 272B: 2-way ~ free; V rows 136B: ~4-way on 8B).
// Single-buffered tiles, 2 barriers/jt:
//   issue loads(jt+1) -> frag reads(jt) -> QK -> exp -> barrier ->
//   ds_write(jt+1) || PV -> barrier
// ---------------------------------------------------------------------------
__global__ __launch_bounds__(256, 2) void attn_mfma(const bf16_t* __restrict__ pfT,
                                                    const bf16_t* __restrict__ riT,
                                                    const bf16_t* __restrict__ pfC,
                                                    const bf16_t* __restrict__ riC,
                                                    const float* __restrict__ zrsum,
                                                    const float* __restrict__ zcsum,
                                                    float* __restrict__ fus)
{
    __shared__ char smem[34816];               // Bs[64][272B] + Vs[128][136B]
    bf16_t* As = (bf16_t*)smem;                // prologue A tile, aliases Bs
    char*   Bs = smem;                         // B tile, padded rows 272B
    char*   Vs = smem + 17408;                 // V tile, padded rows 136B
    float*  Rs = (float*)smem;                 // epilogue 64x65, aliases all

    const int t = threadIdx.x;
    const int blk = blockIdx.x;
    const int g = blk & 7;                     // combo -> XCD
    const int slot = blk >> 3;                 // 0..63 i-slot
    const int b = g & 1, mode = (g >> 1) & 1, js = g >> 2;
    const bf16_t* At = (mode == 0 ? pfT : riT) + (size_t)b * NTOK * PCH;
    const bf16_t* Bt = (mode == 0 ? riT : pfT) + (size_t)b * NTOK * PCH;
    const bf16_t* Vc = (mode == 0 ? pfC : riC) + (size_t)b * PCH * NTOK;
    const float* wsum = (mode == 0 ? zcsum : zrsum) + (size_t)b * NTOK;
    const int lane = t & 63, w = t >> 6, tx = lane & 15, q = lane >> 4;
    const int h = w & 1, jh = w >> 1;
    const int i0 = slot * 64;
    const int jbase = js * 2048;
    const int sr = t >> 4, sc = t & 15;

    // ---- prologue: A tile -> LDS -> af regs
#pragma unroll
    for (int p = 0; p < 4; p++) {
        int i = p * 16 + sr;
        *(uint4*)&As[i * LDK + sc * 8] = *(const uint4*)&At[((size_t)(i0 + i)) * PCH + sc * 8];
    }
    __syncthreads();
    bf16x8 af[2][4];                           // this wave's 32 i-rows, held all kernel
#pragma unroll
    for (int mt = 0; mt < 2; mt++)
#pragma unroll
        for (int s = 0; s < 4; s++)
            af[mt][s] = *(bf16x8*)&As[(h * 32 + mt * 16 + tx) * LDK + s * 32 + q * 8];
    __syncthreads();                           // done with As before B overwrite

    const float* Wp = wsum + jbase + jh * 32 + q * 4;

    // staging registers + helpers (fully unrolled, static indices only)
    uint4 sB[4], sV[4];
    auto stageIssue = [&](int jtn) {
        const char* Bsrc = (const char*)(Bt + (size_t)(jbase + jtn * 64) * PCH);
        const size_t vcol = (size_t)(jbase + jtn * 64) * 2;
#pragma unroll
        for (int p = 0; p < 4; p++)
            sB[p] = *(const uint4*)(Bsrc + t * 16 + p * 4096);
#pragma unroll
        for (int p = 0; p < 4; p++) {
            int o = t * 16 + p * 4096;
            sV[p] = *(const uint4*)((const char*)Vc + (size_t)(o >> 7) * (NTOK * 2) + vcol + (o & 127));
        }
    };
    auto stageWrite = [&]() {
#pragma unroll
        for (int p = 0; p < 4; p++) {
            int o = t * 16 + p * 4096;
            *(uint4*)(Bs + (o >> 8) * 272 + (o & 255)) = sB[p];
        }
#pragma unroll
        for (int p = 0; p < 4; p++) {
            int o = t * 16 + p * 4096;
            *(uint4*)(Vs + (o >> 7) * 136 + (o & 127)) = sV[p];
        }
    };

    // stage tile 0
    stageIssue(0);
    stageWrite();
    float4 wv0 = *(const float4*)&Wp[0];
    float4 wv1 = *(const float4*)&Wp[16];
    float4 wn0 = wv0, wn1 = wv1;
    __syncthreads();

    floatx4 acc[2][8];                         // out[i=h*32+mt*16+q*4+r][d=c*16+tx]
#pragma unroll
    for (int mt = 0; mt < 2; mt++)
#pragma unroll
        for (int c = 0; c < 8; c++) acc[mt][c] = (floatx4){0.f, 0.f, 0.f, 0.f};

#pragma unroll 1
    for (int jt = 0; jt < 32; jt++) {
        // issue next tile's global loads early (consumed by ds_write below)
        if (jt < 31) {
            stageIssue(jt + 1);
            wn0 = *(const float4*)&Wp[(jt + 1) * 64];
            wn1 = *(const float4*)&Wp[(jt + 1) * 64 + 16];
        }
        __builtin_amdgcn_sched_barrier(0);

        // fragment reads from LDS (current tile)
        bf16x8 bcur[2][4];
#pragma unroll
        for (int jm = 0; jm < 2; jm++)
#pragma unroll
            for (int s = 0; s < 4; s++)
                bcur[jm][s] = *(const bf16x8*)(Bs + (jh * 32 + jm * 16 + tx) * 272 + s * 64 + q * 16);
        bf16x8 vcur[8];
#pragma unroll
        for (int c = 0; c < 8; c++) {
            const char* vb = Vs + (tx + c * 16) * 136 + (jh * 32 + q * 4) * 2;
            bf16x4 vlo = *(const bf16x4*)vb;
            bf16x4 vhi = *(const bf16x4*)(vb + 32);
            vcur[c] = __builtin_shufflevector(vlo, vhi, 0, 1, 2, 3, 4, 5, 6, 7);
        }

        // QK: lane(q,tx) reg r = s[j = jt*64+jh*32+jm*16+q*4+r][i = i0+h*32+mt*16+tx]
        __builtin_amdgcn_s_setprio(1);
        floatx4 sx[2][2];
#pragma unroll
        for (int jm = 0; jm < 2; jm++)
#pragma unroll
            for (int mt = 0; mt < 2; mt++) {
                sx[jm][mt] = (floatx4){0.f, 0.f, 0.f, 0.f};
#pragma unroll
                for (int s = 0; s < 4; s++)
                    sx[jm][mt] = __builtin_amdgcn_mfma_f32_16x16x32_bf16(bcur[jm][s], af[mt][s], sx[jm][mt], 0, 0, 0);
            }
        __builtin_amdgcn_s_setprio(0);

        // exp + normalize, packed directly into PV A-frags (e<4: jm0, e>=4: jm1)
        float lz00 = __builtin_amdgcn_logf(wv0.x), lz01 = __builtin_amdgcn_logf(wv0.y);
        float lz02 = __builtin_amdgcn_logf(wv0.z), lz03 = __builtin_amdgcn_logf(wv0.w);
        float lz10 = __builtin_amdgcn_logf(wv1.x), lz11 = __builtin_amdgcn_logf(wv1.y);
        float lz12 = __builtin_amdgcn_logf(wv1.z), lz13 = __builtin_amdgcn_logf(wv1.w);
        bf16x8 ea0 = {
            (bf16_t)__builtin_amdgcn_exp2f(sx[0][0][0] * SCALE2 - lz00),
            (bf16_t)__builtin_amdgcn_exp2f(sx[0][0][1] * SCALE2 - lz01),
            (bf16_t)__builtin_amdgcn_exp2f(sx[0][0][2] * SCALE2 - lz02),
            (bf16_t)__builtin_amdgcn_exp2f(sx[0][0][3] * SCALE2 - lz03),
            (bf16_t)__builtin_amdgcn_exp2f(sx[1][0][0] * SCALE2 - lz10),
            (bf16_t)__builtin_amdgcn_exp2f(sx[1][0][1] * SCALE2 - lz11),
            (bf16_t)__builtin_amdgcn_exp2f(sx[1][0][2] * SCALE2 - lz12),
            (bf16_t)__builtin_amdgcn_exp2f(sx[1][0][3] * SCALE2 - lz13) };
        bf16x8 ea1 = {
            (bf16_t)__builtin_amdgcn_exp2f(sx[0][1][0] * SCALE2 - lz00),
            (bf16_t)__builtin_amdgcn_exp2f(sx[0][1][1] * SCALE2 - lz01),
            (bf16_t)__builtin_amdgcn_exp2f(sx[0][1][2] * SCALE2 - lz02),
            (bf16_t)__builtin_amdgcn_exp2f(sx[0][1][3] * SCALE2 - lz03),
            (bf16_t)__builtin_amdgcn_exp2f(sx[1][1][0] * SCALE2 - lz10),
            (bf16_t)__builtin_amdgcn_exp2f(sx[1][1][1] * SCALE2 - lz11),
            (bf16_t)__builtin_amdgcn_exp2f(sx[1][1][2] * SCALE2 - lz12),
            (bf16_t)__builtin_amdgcn_exp2f(sx[1][1][3] * SCALE2 - lz13) };

        __syncthreads();                       // all frag reads done block-wide

        // overwrite tiles with jt+1 (overlaps PV below)
        if (jt < 31) stageWrite();

        // PV: 16 independent mfma, acc[mt][c] += E[i][j] * V[j][d]
        __builtin_amdgcn_s_setprio(1);
#pragma unroll
        for (int c = 0; c < 8; c++) {
            acc[0][c] = __builtin_amdgcn_mfma_f32_16x16x32_bf16(ea0, vcur[c], acc[0][c], 0, 0, 0);
            acc[1][c] = __builtin_amdgcn_mfma_f32_16x16x32_bf16(ea1, vcur[c], acc[1][c], 0, 0, 0);
        }
        __builtin_amdgcn_s_setprio(0);

        __syncthreads();                       // writes visible for next iter
        wv0 = wn0; wv1 = wn1;
    }

    // epilogue: cross-wave reduce (jh pairs) in LDS, then COALESCED atomics:
    // wave w owns rows w*16..w*16+15, lane = d (64 consecutive floats/instr).
    __syncthreads();
#pragma unroll
    for (int half = 0; half < 2; half++) {
        for (int k = t; k < 64 * 65; k += 256) Rs[k] = 0.f;
        __syncthreads();
#pragma unroll
        for (int mt = 0; mt < 2; mt++)
#pragma unroll
            for (int c = 0; c < 4; c++)
#pragma unroll
                for (int r = 0; r < 4; r++)
                    atomicAdd(&Rs[(h * 32 + mt * 16 + q * 4 + r) * 65 + c * 16 + tx],
                              acc[mt][half * 4 + c][r]);
        __syncthreads();
        {
            float* fo = fus + ((size_t)(b * NTOK + i0)) * 256 + mode * 128 + half * 64;
#pragma unroll
            for (int k = 0; k < 16; k++) {
                const int row = w * 16 + k;
                atomicAdd(&fo[(size_t)row * 256 + lane], Rs[row * 65 + lane]);
            }
        }
        __syncthreads();
    }
}

// ---------------------------------------------------------------------------
// K4: conv (MFMA) — out[o][n] = relu(bn(sum_c cw[o][c]*fus[n][c] + cb))
// ---------------------------------------------------------------------------
__global__ __launch_bounds__(256) void conv_mfma(const float* __restrict__ fus,
                                                 const float* __restrict__ cw,
                                                 const float* __restrict__ cb,
                                                 const float* __restrict__ g,
                                                 const float* __restrict__ be,
                                                 const float* __restrict__ mu,
                                                 const float* __restrict__ var,
                                                 float* __restrict__ out)
{
    const int t = threadIdx.x;
    const int n0 = blockIdx.x * 64, obase = blockIdx.y * 64, b = blockIdx.z;
    const int lane = t & 63, wv = t >> 6, tx = lane & 15, q = lane >> 4;
    const int n = n0 + wv * 16 + tx;
    const float* frow = fus + ((size_t)(b * NTOK + n)) * 256;

    floatx4 acc[4];
#pragma unroll
    for (int ot = 0; ot < 4; ot++) acc[ot] = (floatx4){0.f, 0.f, 0.f, 0.f};

#pragma unroll
    for (int s = 0; s < 8; s++) {
        float4 f0 = *(const float4*)&frow[s * 32 + q * 8];
        float4 f1 = *(const float4*)&frow[s * 32 + q * 8 + 4];
        bf16x8 bf;
        bf[0] = (bf16_t)f0.x; bf[1] = (bf16_t)f0.y; bf[2] = (bf16_t)f0.z; bf[3] = (bf16_t)f0.w;
        bf[4] = (bf16_t)f1.x; bf[5] = (bf16_t)f1.y; bf[6] = (bf16_t)f1.z; bf[7] = (bf16_t)f1.w;
#pragma unroll
        for (int ot = 0; ot < 4; ot++) {
            const float* wr = cw + (size_t)(obase + ot * 16 + tx) * 256 + s * 32 + q * 8;
            float4 x0 = *(const float4*)wr;
            float4 x1 = *(const float4*)(wr + 4);
            bf16x8 af;
            af[0] = (bf16_t)x0.x; af[1] = (bf16_t)x0.y; af[2] = (bf16_t)x0.z; af[3] = (bf16_t)x0.w;
            af[4] = (bf16_t)x1.x; af[5] = (bf16_t)x1.y; af[6] = (bf16_t)x1.z; af[7] = (bf16_t)x1.w;
            acc[ot] = __builtin_amdgcn_mfma_f32_16x16x32_bf16(af, bf, acc[ot], 0, 0, 0);
        }
    }

#pragma unroll
    for (int ot = 0; ot < 4; ot++)
#pragma unroll
        for (int r = 0; r < 4; r++) {
            const int o = obase + ot * 16 + q * 4 + r;
            const float sc = g[o] * rsqrtf(var[o] + 1e-5f);
            const float b0 = be[o] + (cb[o] - mu[o]) * sc;
            float y = acc[ot][r] * sc + b0;
            out[((size_t)(b * OCH + o)) * NTOK + n] = fmaxf(y, 0.f);
        }
}

// ---------------------------------------------------------------------------
extern "C" void kernel_launch(void* const* d_in, const int* in_sizes, int n_in,
                              void* d_out, int out_size, void* d_ws, size_t ws_size,
                              hipStream_t stream)
{
    const float* pf   = (const float*)d_in[0];
    const float* img  = (const float*)d_in[1];
    const float* fc2w = (const float*)d_in[2];
    const float* fc2b = (const float*)d_in[3];
    const float* cw   = (const float*)d_in[4];
    const float* cb   = (const float*)d_in[5];
    const float* g    = (const float*)d_in[6];
    const float* be   = (const float*)d_in[7];
    const float* mu   = (const float*)d_in[8];
    const float* var  = (const float*)d_in[9];
    float* out = (float*)d_out;

    // ws layout: proven footprint (16,842,752 B). imgT aliases fus region
    // (dead after fc2; fus is zeroed inside stats which runs after fc2).
    float* fus   = (float*)d_ws;                              // 8 MB
    float* zrsum = fus + (size_t)NB * NTOK * 256;             // 32 KB
    float* zcsum = zrsum + NB * NTOK;                         // 32 KB (contiguous after zrsum)
    bf16_t* pfC = (bf16_t*)(zcsum + NB * NTOK);               // 2 MB
    bf16_t* pfT = pfC + (size_t)NB * PCH * NTOK;              // 2 MB
    bf16_t* riC = pfT + (size_t)NB * NTOK * PCH;              // 2 MB
    bf16_t* riT = riC + (size_t)NB * PCH * NTOK;              // 2 MB
    bf16_t* imgT = (bf16_t*)fus;                              // 4 MB alias

    pack_all  <<<dim3(64, 6, NB), 256, 0, stream>>>(pf, img, pfC, pfT, imgT);
    fc2_mfma  <<<dim3(64, 2, NB), 256, 0, stream>>>(imgT, fc2w, fc2b, riC, riT, zrsum);
    stats_mfma<<<dim3(512),       256, 0, stream>>>(pfT, riT, zrsum, zcsum, fus);
    attn_mfma <<<dim3(512),       256, 0, stream>>>(pfT, riT, pfC, riC, zrsum, zcsum, fus);
    conv_mfma <<<dim3(64, 2, NB), 256, 0, stream>>>(fus, cw, cb, g, be, mu, var, out);
}

// Round 5
// 234.897 us; speedup vs baseline: 2.1175x; 1.4090x over previous
//
#include <hip/hip_runtime.h>
#include <math.h>

// Problem constants
#define NTOK 4096
#define PCH  128
#define ICH  256
#define OCH  128
#define NB   2
#define SCALEF 0.08838834764831845f   // 1/sqrt(128)
#define SCALE2 0.12751743f            // SCALEF * log2(e)

typedef __bf16 bf16_t;
typedef __attribute__((ext_vector_type(8))) __bf16 bf16x8;
typedef __attribute__((ext_vector_type(4))) __bf16 bf16x4;
typedef __attribute__((ext_vector_type(4))) float floatx4;

#define LDK 136   // padded row length (bf16) for k=128 tiles

// ---------------------------------------------------------------------------
// K0: merged pack — y<2: pf -> pfC + pfT;  y>=2: img -> imgT (token-major)
// ---------------------------------------------------------------------------
__global__ __launch_bounds__(256) void pack_all(const float* __restrict__ pf,
                                                const float* __restrict__ img,
                                                bf16_t* __restrict__ pfC,
                                                bf16_t* __restrict__ pfT,
                                                bf16_t* __restrict__ imgT)
{
    __shared__ float Ls[64][65];
    const int t = threadIdx.x;
    const int n0 = blockIdx.x * 64, b = blockIdx.z;
    const bool ispf = blockIdx.y < 2;
    const int d0 = ispf ? blockIdx.y * 64 : (blockIdx.y - 2) * 64;
    const float* src = (ispf ? pf + ((size_t)(b * PCH + d0)) * NTOK
                             : img + ((size_t)(b * ICH + d0)) * NTOK) + n0;
#pragma unroll
    for (int p = 0; p < 4; p++) {
        int d = p * 16 + (t >> 4), c = t & 15;
        float4 v = *(const float4*)&src[d * NTOK + c * 4];
        Ls[d][c * 4 + 0] = v.x; Ls[d][c * 4 + 1] = v.y;
        Ls[d][c * 4 + 2] = v.z; Ls[d][c * 4 + 3] = v.w;
        if (ispf) {
            bf16x4 o = { (bf16_t)v.x, (bf16_t)v.y, (bf16_t)v.z, (bf16_t)v.w };
            *(bf16x4*)&pfC[((size_t)(b * PCH + d0 + d)) * NTOK + n0 + c * 4] = o;
        }
    }
    __syncthreads();
#pragma unroll
    for (int p = 0; p < 2; p++) {
        int n = p * 32 + (t >> 3), c = t & 7;
        bf16x8 o;
#pragma unroll
        for (int k = 0; k < 8; k++) o[k] = (bf16_t)Ls[c * 8 + k][n];
        if (ispf)
            *(bf16x8*)&pfT[((size_t)(b * NTOK + n0 + n)) * PCH + d0 + c * 8] = o;
        else
            *(bf16x8*)&imgT[((size_t)(b * NTOK + n0 + n)) * ICH + d0 + c * 8] = o;
    }
}

// ---------------------------------------------------------------------------
// K1: fc2 (MFMA) — ri[p][n] = sum_c w[p][c]*img[c][n] + bias[p]
// Also zeroes the zsum buffers (16384 floats) in its prologue.
// ---------------------------------------------------------------------------
__global__ __launch_bounds__(256) void fc2_mfma(const bf16_t* __restrict__ imgT,
                                                const float* __restrict__ w,
                                                const float* __restrict__ bias,
                                                bf16_t* __restrict__ riC,
                                                bf16_t* __restrict__ riT,
                                                float* __restrict__ zsums)
{
    const int t = threadIdx.x;
    if (blockIdx.y == 0 && blockIdx.z == 0)
        zsums[blockIdx.x * 256 + t] = 0.f;       // 64 blocks x 256 = 16384 floats

    const int n0 = blockIdx.x * 64, pbase = blockIdx.y * 64, b = blockIdx.z;
    const int lane = t & 63, wv = t >> 6, tx = lane & 15, q = lane >> 4;
    const int n = n0 + wv * 16 + tx;
    const bf16_t* trow = imgT + ((size_t)(b * NTOK + n)) * ICH;

    floatx4 acc[4];
#pragma unroll
    for (int ot = 0; ot < 4; ot++) acc[ot] = (floatx4){0.f, 0.f, 0.f, 0.f};

#pragma unroll
    for (int s = 0; s < 8; s++) {
        bf16x8 bf = *(const bf16x8*)&trow[s * 32 + q * 8];
#pragma unroll
        for (int ot = 0; ot < 4; ot++) {
            const float* wr = w + (size_t)(pbase + ot * 16 + tx) * ICH + s * 32 + q * 8;
            float4 x0 = *(const float4*)wr;
            float4 x1 = *(const float4*)(wr + 4);
            bf16x8 af;
            af[0] = (bf16_t)x0.x; af[1] = (bf16_t)x0.y; af[2] = (bf16_t)x0.z; af[3] = (bf16_t)x0.w;
            af[4] = (bf16_t)x1.x; af[5] = (bf16_t)x1.y; af[6] = (bf16_t)x1.z; af[7] = (bf16_t)x1.w;
            acc[ot] = __builtin_amdgcn_mfma_f32_16x16x32_bf16(af, bf, acc[ot], 0, 0, 0);
        }
    }

#pragma unroll
    for (int ot = 0; ot < 4; ot++) {
        bf16x4 tv;
#pragma unroll
        for (int r = 0; r < 4; r++) {
            const int p = pbase + ot * 16 + q * 4 + r;
            float v = acc[ot][r] + bias[p];
            tv[r] = (bf16_t)v;
            riC[((size_t)(b * PCH + p)) * NTOK + n] = (bf16_t)v;
        }
        *(bf16x4*)&riT[((size_t)(b * NTOK + n)) * PCH + pbase + ot * 16 + q * 4] = tv;
    }
}

// ---------------------------------------------------------------------------
// K2: stats v5 + XCD swizzle + fus-zero prologue (unchanged).
// ---------------------------------------------------------------------------
__global__ __launch_bounds__(256, 4) void stats_mfma(const bf16_t* __restrict__ pfT,
                                                     const bf16_t* __restrict__ riT,
                                                     float* __restrict__ zr,
                                                     float* __restrict__ zc,
                                                     float* __restrict__ fus)
{
    __shared__ bf16_t As[64 * LDK];
    __shared__ float zacc[1024];
    const int t = threadIdx.x;
    const int blk = blockIdx.x;

    { // zero fus: 512 blocks x 256 thr x 4 float4 = 2,097,152 floats exactly
        float4* f4 = (float4*)fus + ((size_t)blk * 256 + t) * 4;
        f4[0] = float4{0.f, 0.f, 0.f, 0.f};
        f4[1] = float4{0.f, 0.f, 0.f, 0.f};
        f4[2] = float4{0.f, 0.f, 0.f, 0.f};
        f4[3] = float4{0.f, 0.f, 0.f, 0.f};
    }

    const int g = blk & 7, slot = blk >> 3;      // XCD-aware decode
    const int b = g & 1, js = g >> 1;
    const bf16_t* At = pfT + (size_t)b * NTOK * PCH;
    const bf16_t* Bt = riT + (size_t)b * NTOK * PCH;
    float* zrow = zr + (size_t)b * NTOK;
    float* zcol = zc + (size_t)b * NTOK;
    const int lane = t & 63, w = t >> 6, tx = lane & 15, q = lane >> 4;
    const int i0 = slot * 64;
    const int jbase = js * 1024;
    const int sr = t >> 4, sc = t & 15;
    const bf16_t* Brow = Bt + (size_t)(jbase + w * 16 + tx) * PCH;

    bf16x8 bcur[4];
#pragma unroll
    for (int s = 0; s < 4; s++)
        bcur[s] = *(const bf16x8*)&Brow[s * 32 + q * 8];
#pragma unroll
    for (int p = 0; p < 4; p++) {
        int i = p * 16 + sr;
        *(uint4*)&As[i * LDK + sc * 8] = *(const uint4*)&At[((size_t)(i0 + i)) * PCH + sc * 8];
    }
    __syncthreads();
    bf16x8 af[4][4];
#pragma unroll
    for (int mt = 0; mt < 4; mt++)
#pragma unroll
        for (int s = 0; s < 4; s++)
            af[mt][s] = *(bf16x8*)&As[(mt * 16 + tx) * LDK + s * 32 + q * 8];

    float racc[4] = {0.f, 0.f, 0.f, 0.f};
    for (int jt = 0; jt < 16; jt++) {
        __builtin_amdgcn_s_barrier();            // pacing only
        floatx4 sacc[4];
#pragma unroll
        for (int mt = 0; mt < 4; mt++) {
            sacc[mt] = (floatx4){0.f, 0.f, 0.f, 0.f};
#pragma unroll
            for (int s = 0; s < 4; s++)
                sacc[mt] = __builtin_amdgcn_mfma_f32_16x16x32_bf16(bcur[s], af[mt][s], sacc[mt], 0, 0, 0);
        }
        if (jt < 15) {
            const bf16_t* bn = Brow + (size_t)(jt + 1) * 64 * PCH;
#pragma unroll
            for (int s = 0; s < 4; s++)
                bcur[s] = *(const bf16x8*)&bn[s * 32 + q * 8];
        }

        float ctmp[4] = {0.f, 0.f, 0.f, 0.f};
#pragma unroll
        for (int mt = 0; mt < 4; mt++)
#pragma unroll
            for (int r = 0; r < 4; r++) {
                float e = __expf(sacc[mt][r] * SCALEF);
                racc[mt] += e;
                ctmp[r]  += e;
            }
#pragma unroll
        for (int r = 0; r < 4; r++) {
            float v = ctmp[r];
            v += __shfl_xor(v, 1); v += __shfl_xor(v, 2);
            v += __shfl_xor(v, 4); v += __shfl_xor(v, 8);
            if (tx == 0) zacc[jt * 64 + w * 16 + q * 4 + r] = v;
        }
    }
#pragma unroll
    for (int mt = 0; mt < 4; mt++) {
        float v = racc[mt];
        v += __shfl_xor(v, 16);
        v += __shfl_xor(v, 32);
        if (q == 0) atomicAdd(&zrow[i0 + mt * 16 + tx], v);
    }
    __syncthreads();
#pragma unroll
    for (int k = 0; k < 4; k++)
        atomicAdd(&zcol[jbase + k * 256 + t], zacc[k * 256 + t]);
}

// ---------------------------------------------------------------------------
// K3: attn v6 — v5 structure with the staging ALLOCA eliminated.
// R4 diagnosis: v5's sB[4]/sV[4] arrays were captured BY REFERENCE in
// lambdas -> address-taken before inlining -> SROA failed -> stage regs
// became scratch (WRITE_SIZE 16->205 MB, VGPR stuck at 116, dur unchanged
// 205us: the per-jt serial chain just swapped L2-gather latency for
// scratch round-trip latency). v6: NO lambdas, NO arrays in the staging
// path — 8 individually named uint4 registers + precomputed base pointers
// with literal offsets. Everything else (verified QK->softmax->PV register
// dataflow, 2-barrier/jt schedule, coalesced atomic epilogue) unchanged.
// ---------------------------------------------------------------------------
__global__ __launch_bounds__(256, 2) void attn_mfma(const bf16_t* __restrict__ pfT,
                                                    const bf16_t* __restrict__ riT,
                                                    const bf16_t* __restrict__ pfC,
                                                    const bf16_t* __restrict__ riC,
                                                    const float* __restrict__ zrsum,
                                                    const float* __restrict__ zcsum,
                                                    float* __restrict__ fus)
{
    __shared__ char smem[34816];               // Bs[64][272B] + Vs[128][136B]
    bf16_t* As = (bf16_t*)smem;                // prologue A tile, aliases Bs
    char*   Bs = smem;                         // B tile, padded rows 272B
    char*   Vs = smem + 17408;                 // V tile, padded rows 136B
    float*  Rs = (float*)smem;                 // epilogue 64x65, aliases all

    const int t = threadIdx.x;
    const int blk = blockIdx.x;
    const int g = blk & 7;                     // combo -> XCD
    const int slot = blk >> 3;                 // 0..63 i-slot
    const int b = g & 1, mode = (g >> 1) & 1, js = g >> 2;
    const bf16_t* At = (mode == 0 ? pfT : riT) + (size_t)b * NTOK * PCH;
    const bf16_t* Bt = (mode == 0 ? riT : pfT) + (size_t)b * NTOK * PCH;
    const bf16_t* Vc = (mode == 0 ? pfC : riC) + (size_t)b * PCH * NTOK;
    const float* wsum = (mode == 0 ? zcsum : zrsum) + (size_t)b * NTOK;
    const int lane = t & 63, w = t >> 6, tx = lane & 15, q = lane >> 4;
    const int h = w & 1, jh = w >> 1;
    const int i0 = slot * 64;
    const int jbase = js * 2048;
    const int sr = t >> 4, sc = t & 15;

    // ---- prologue: A tile -> LDS -> af regs
#pragma unroll
    for (int p = 0; p < 4; p++) {
        int i = p * 16 + sr;
        *(uint4*)&As[i * LDK + sc * 8] = *(const uint4*)&At[((size_t)(i0 + i)) * PCH + sc * 8];
    }
    __syncthreads();
    bf16x8 af[2][4];                           // this wave's 32 i-rows, held all kernel
#pragma unroll
    for (int mt = 0; mt < 2; mt++)
#pragma unroll
        for (int s = 0; s < 4; s++)
            af[mt][s] = *(bf16x8*)&As[(h * 32 + mt * 16 + tx) * LDK + s * 32 + q * 8];
    __syncthreads();                           // done with As before B overwrite

    const float* Wp = wsum + jbase + jh * 32 + q * 4;

    // staging bases: per-thread invariant; per-jt offsets are literals.
    // B tile: row (t>>4)+p*16 of 64 rows x 256B (contiguous global);
    //         LDS rows padded to 272B.
    // V tile: row (t>>3)+p*32 of 128 rows x 128B (global row stride 8KB);
    //         LDS rows padded to 136B.
    const char* BsrcB = (const char*)Bt + (size_t)jbase * 256 + t * 16;
    const char* VsrcB = (const char*)Vc + (size_t)(t >> 3) * (NTOK * 2)
                        + (size_t)jbase * 2 + (t & 7) * 16;
    char* Bdst = Bs + (t >> 4) * 272 + (t & 15) * 16;
    char* Vdst = Vs + (t >> 3) * 136 + (t & 7) * 16;

    uint4 sB0, sB1, sB2, sB3, sV0, sV1, sV2, sV3;

#define STAGE_ISSUE(jtn)                                                        \
    sB0 = *(const uint4*)(BsrcB + (size_t)(jtn) * 16384);                       \
    sB1 = *(const uint4*)(BsrcB + (size_t)(jtn) * 16384 + 4096);                \
    sB2 = *(const uint4*)(BsrcB + (size_t)(jtn) * 16384 + 8192);                \
    sB3 = *(const uint4*)(BsrcB + (size_t)(jtn) * 16384 + 12288);               \
    sV0 = *(const uint4*)(VsrcB + (size_t)(jtn) * 128);                         \
    sV1 = *(const uint4*)(VsrcB + (size_t)(jtn) * 128 + (size_t)32 * NTOK * 2); \
    sV2 = *(const uint4*)(VsrcB + (size_t)(jtn) * 128 + (size_t)64 * NTOK * 2); \
    sV3 = *(const uint4*)(VsrcB + (size_t)(jtn) * 128 + (size_t)96 * NTOK * 2);

#define STAGE_WRITE()                  \
    *(uint4*)(Bdst)            = sB0;  \
    *(uint4*)(Bdst + 16 * 272) = sB1;  \
    *(uint4*)(Bdst + 32 * 272) = sB2;  \
    *(uint4*)(Bdst + 48 * 272) = sB3;  \
    *(uint4*)(Vdst)            = sV0;  \
    *(uint4*)(Vdst + 32 * 136) = sV1;  \
    *(uint4*)(Vdst + 64 * 136) = sV2;  \
    *(uint4*)(Vdst + 96 * 136) = sV3;

    // stage tile 0
    STAGE_ISSUE(0)
    STAGE_WRITE()
    float4 wv0 = *(const float4*)&Wp[0];
    float4 wv1 = *(const float4*)&Wp[16];
    float4 wn0 = wv0, wn1 = wv1;
    __syncthreads();

    floatx4 acc[2][8];                         // out[i=h*32+mt*16+q*4+r][d=c*16+tx]
#pragma unroll
    for (int mt = 0; mt < 2; mt++)
#pragma unroll
        for (int c = 0; c < 8; c++) acc[mt][c] = (floatx4){0.f, 0.f, 0.f, 0.f};

#pragma unroll 1
    for (int jt = 0; jt < 32; jt++) {
        // issue next tile's global loads early (consumed by ds_write below)
        if (jt < 31) {
            STAGE_ISSUE(jt + 1)
            wn0 = *(const float4*)&Wp[(jt + 1) * 64];
            wn1 = *(const float4*)&Wp[(jt + 1) * 64 + 16];
        }
        __builtin_amdgcn_sched_barrier(0);

        // fragment reads from LDS (current tile)
        bf16x8 bcur[2][4];
#pragma unroll
        for (int jm = 0; jm < 2; jm++)
#pragma unroll
            for (int s = 0; s < 4; s++)
                bcur[jm][s] = *(const bf16x8*)(Bs + (jh * 32 + jm * 16 + tx) * 272 + s * 64 + q * 16);
        bf16x8 vcur[8];
#pragma unroll
        for (int c = 0; c < 8; c++) {
            const char* vb = Vs + (tx + c * 16) * 136 + (jh * 32 + q * 4) * 2;
            bf16x4 vlo = *(const bf16x4*)vb;
            bf16x4 vhi = *(const bf16x4*)(vb + 32);
            vcur[c] = __builtin_shufflevector(vlo, vhi, 0, 1, 2, 3, 4, 5, 6, 7);
        }

        // QK: lane(q,tx) reg r = s[j = jt*64+jh*32+jm*16+q*4+r][i = i0+h*32+mt*16+tx]
        __builtin_amdgcn_s_setprio(1);
        floatx4 sx[2][2];
#pragma unroll
        for (int jm = 0; jm < 2; jm++)
#pragma unroll
            for (int mt = 0; mt < 2; mt++) {
                sx[jm][mt] = (floatx4){0.f, 0.f, 0.f, 0.f};
#pragma unroll
                for (int s = 0; s < 4; s++)
                    sx[jm][mt] = __builtin_amdgcn_mfma_f32_16x16x32_bf16(bcur[jm][s], af[mt][s], sx[jm][mt], 0, 0, 0);
            }
        __builtin_amdgcn_s_setprio(0);

        // exp + normalize, packed directly into PV A-frags (e<4: jm0, e>=4: jm1)
        float lz00 = __builtin_amdgcn_logf(wv0.x), lz01 = __builtin_amdgcn_logf(wv0.y);
        float lz02 = __builtin_amdgcn_logf(wv0.z), lz03 = __builtin_amdgcn_logf(wv0.w);
        float lz10 = __builtin_amdgcn_logf(wv1.x), lz11 = __builtin_amdgcn_logf(wv1.y);
        float lz12 = __builtin_amdgcn_logf(wv1.z), lz13 = __builtin_amdgcn_logf(wv1.w);
        bf16x8 ea0 = {
            (bf16_t)__builtin_amdgcn_exp2f(sx[0][0][0] * SCALE2 - lz00),
            (bf16_t)__builtin_amdgcn_exp2f(sx[0][0][1] * SCALE2 - lz01),
            (bf16_t)__builtin_amdgcn_exp2f(sx[0][0][2] * SCALE2 - lz02),
            (bf16_t)__builtin_amdgcn_exp2f(sx[0][0][3] * SCALE2 - lz03),
            (bf16_t)__builtin_amdgcn_exp2f(sx[1][0][0] * SCALE2 - lz10),
            (bf16_t)__builtin_amdgcn_exp2f(sx[1][0][1] * SCALE2 - lz11),
            (bf16_t)__builtin_amdgcn_exp2f(sx[1][0][2] * SCALE2 - lz12),
            (bf16_t)__builtin_amdgcn_exp2f(sx[1][0][3] * SCALE2 - lz13) };
        bf16x8 ea1 = {
            (bf16_t)__builtin_amdgcn_exp2f(sx[0][1][0] * SCALE2 - lz00),
            (bf16_t)__builtin_amdgcn_exp2f(sx[0][1][1] * SCALE2 - lz01),
            (bf16_t)__builtin_amdgcn_exp2f(sx[0][1][2] * SCALE2 - lz02),
            (bf16_t)__builtin_amdgcn_exp2f(sx[0][1][3] * SCALE2 - lz03),
            (bf16_t)__builtin_amdgcn_exp2f(sx[1][1][0] * SCALE2 - lz10),
            (bf16_t)__builtin_amdgcn_exp2f(sx[1][1][1] * SCALE2 - lz11),
            (bf16_t)__builtin_amdgcn_exp2f(sx[1][1][2] * SCALE2 - lz12),
            (bf16_t)__builtin_amdgcn_exp2f(sx[1][1][3] * SCALE2 - lz13) };

        __syncthreads();                       // all frag reads done block-wide

        // overwrite tiles with jt+1 (overlaps PV below)
        if (jt < 31) { STAGE_WRITE() }

        // PV: 16 independent mfma, acc[mt][c] += E[i][j] * V[j][d]
        __builtin_amdgcn_s_setprio(1);
#pragma unroll
        for (int c = 0; c < 8; c++) {
            acc[0][c] = __builtin_amdgcn_mfma_f32_16x16x32_bf16(ea0, vcur[c], acc[0][c], 0, 0, 0);
            acc[1][c] = __builtin_amdgcn_mfma_f32_16x16x32_bf16(ea1, vcur[c], acc[1][c], 0, 0, 0);
        }
        __builtin_amdgcn_s_setprio(0);

        __syncthreads();                       // writes visible for next iter
        wv0 = wn0; wv1 = wn1;
    }
#undef STAGE_ISSUE
#undef STAGE_WRITE

    // epilogue: cross-wave reduce (jh pairs) in LDS, then COALESCED atomics:
    // wave w owns rows w*16..w*16+15, lane = d (64 consecutive floats/instr).
    __syncthreads();
#pragma unroll
    for (int half = 0; half < 2; half++) {
        for (int k = t; k < 64 * 65; k += 256) Rs[k] = 0.f;
        __syncthreads();
#pragma unroll
        for (int mt = 0; mt < 2; mt++)
#pragma unroll
            for (int c = 0; c < 4; c++)
#pragma unroll
                for (int r = 0; r < 4; r++)
                    atomicAdd(&Rs[(h * 32 + mt * 16 + q * 4 + r) * 65 + c * 16 + tx],
                              acc[mt][half * 4 + c][r]);
        __syncthreads();
        {
            float* fo = fus + ((size_t)(b * NTOK + i0)) * 256 + mode * 128 + half * 64;
#pragma unroll
            for (int k = 0; k < 16; k++) {
                const int row = w * 16 + k;
                atomicAdd(&fo[(size_t)row * 256 + lane], Rs[row * 65 + lane]);
            }
        }
        __syncthreads();
    }
}

// ---------------------------------------------------------------------------
// K4: conv (MFMA) — out[o][n] = relu(bn(sum_c cw[o][c]*fus[n][c] + cb))
// ---------------------------------------------------------------------------
__global__ __launch_bounds__(256) void conv_mfma(const float* __restrict__ fus,
                                                 const float* __restrict__ cw,
                                                 const float* __restrict__ cb,
                                                 const float* __restrict__ g,
                                                 const float* __restrict__ be,
                                                 const float* __restrict__ mu,
                                                 const float* __restrict__ var,
                                                 float* __restrict__ out)
{
    const int t = threadIdx.x;
    const int n0 = blockIdx.x * 64, obase = blockIdx.y * 64, b = blockIdx.z;
    const int lane = t & 63, wv = t >> 6, tx = lane & 15, q = lane >> 4;
    const int n = n0 + wv * 16 + tx;
    const float* frow = fus + ((size_t)(b * NTOK + n)) * 256;

    floatx4 acc[4];
#pragma unroll
    for (int ot = 0; ot < 4; ot++) acc[ot] = (floatx4){0.f, 0.f, 0.f, 0.f};

#pragma unroll
    for (int s = 0; s < 8; s++) {
        float4 f0 = *(const float4*)&frow[s * 32 + q * 8];
        float4 f1 = *(const float4*)&frow[s * 32 + q * 8 + 4];
        bf16x8 bf;
        bf[0] = (bf16_t)f0.x; bf[1] = (bf16_t)f0.y; bf[2] = (bf16_t)f0.z; bf[3] = (bf16_t)f0.w;
        bf[4] = (bf16_t)f1.x; bf[5] = (bf16_t)f1.y; bf[6] = (bf16_t)f1.z; bf[7] = (bf16_t)f1.w;
#pragma unroll
        for (int ot = 0; ot < 4; ot++) {
            const float* wr = cw + (size_t)(obase + ot * 16 + tx) * 256 + s * 32 + q * 8;
            float4 x0 = *(const float4*)wr;
            float4 x1 = *(const float4*)(wr + 4);
            bf16x8 af;
            af[0] = (bf16_t)x0.x; af[1] = (bf16_t)x0.y; af[2] = (bf16_t)x0.z; af[3] = (bf16_t)x0.w;
            af[4] = (bf16_t)x1.x; af[5] = (bf16_t)x1.y; af[6] = (bf16_t)x1.z; af[7] = (bf16_t)x1.w;
            acc[ot] = __builtin_amdgcn_mfma_f32_16x16x32_bf16(af, bf, acc[ot], 0, 0, 0);
        }
    }

#pragma unroll
    for (int ot = 0; ot < 4; ot++)
#pragma unroll
        for (int r = 0; r < 4; r++) {
            const int o = obase + ot * 16 + q * 4 + r;
            const float sc = g[o] * rsqrtf(var[o] + 1e-5f);
            const float b0 = be[o] + (cb[o] - mu[o]) * sc;
            float y = acc[ot][r] * sc + b0;
            out[((size_t)(b * OCH + o)) * NTOK + n] = fmaxf(y, 0.f);
        }
}

// ---------------------------------------------------------------------------
extern "C" void kernel_launch(void* const* d_in, const int* in_sizes, int n_in,
                              void* d_out, int out_size, void* d_ws, size_t ws_size,
                              hipStream_t stream)
{
    const float* pf   = (const float*)d_in[0];
    const float* img  = (const float*)d_in[1];
    const float* fc2w = (const float*)d_in[2];
    const float* fc2b = (const float*)d_in[3];
    const float* cw   = (const float*)d_in[4];
    const float* cb   = (const float*)d_in[5];
    const float* g    = (const float*)d_in[6];
    const float* be   = (const float*)d_in[7];
    const float* mu   = (const float*)d_in[8];
    const float* var  = (const float*)d_in[9];
    float* out = (float*)d_out;

    // ws layout: proven footprint (16,842,752 B). imgT aliases fus region
    // (dead after fc2; fus is zeroed inside stats which runs after fc2).
    float* fus   = (float*)d_ws;                              // 8 MB
    float* zrsum = fus + (size_t)NB * NTOK * 256;             // 32 KB
    float* zcsum = zrsum + NB * NTOK;                         // 32 KB (contiguous after zrsum)
    bf16_t* pfC = (bf16_t*)(zcsum + NB * NTOK);               // 2 MB
    bf16_t* pfT = pfC + (size_t)NB * PCH * NTOK;              // 2 MB
    bf16_t* riC = pfT + (size_t)NB * NTOK * PCH;              // 2 MB
    bf16_t* riT = riC + (size_t)NB * PCH * NTOK;              // 2 MB
    bf16_t* imgT = (bf16_t*)fus;                              // 4 MB alias

    pack_all  <<<dim3(64, 6, NB), 256, 0, stream>>>(pf, img, pfC, pfT, imgT);
    fc2_mfma  <<<dim3(64, 2, NB), 256, 0, stream>>>(imgT, fc2w, fc2b, riC, riT, zrsum);
    stats_mfma<<<dim3(512),       256, 0, stream>>>(pfT, riT, zrsum, zcsum, fus);
    attn_mfma <<<dim3(512),       256, 0, stream>>>(pfT, riT, pfC, riC, zrsum, zcsum, fus);
    conv_mfma <<<dim3(64, 2, NB), 256, 0, stream>>>(fus, cw, cb, g, be, mu, var, out);
}